// Round 1
// baseline (1728.897 us; speedup 1.0000x reference)
//
#include <hip/hip_runtime.h>

#define NEG_SLOPE 0.2f

__device__ __forceinline__ float lrelu(float a) { return a > 0.f ? a : NEG_SLOPE * a; }

// ---------------- CSR build ----------------

__global__ void hist_kernel(const int* __restrict__ dst, int E, int* __restrict__ deg) {
    int i = blockIdx.x * blockDim.x + threadIdx.x;
    int stride = gridDim.x * blockDim.x;
    for (int e = i; e < E; e += stride) atomicAdd(&deg[dst[e]], 1);
}

// exclusive rowptr over (deg[n] + 1 self-loop), single 1024-thread block, wave-level scan
__global__ __launch_bounds__(1024) void scan_kernel(const int* __restrict__ deg,
                                                    int* __restrict__ rowptr, int N) {
    __shared__ int wsum[16];
    int t = threadIdx.x, lane = t & 63, w = t >> 6;
    int carry = 0;
    for (int base = 0; base < N; base += 1024) {
        int i = base + t;
        int v = (i < N) ? deg[i] + 1 : 0;
        int s = v;
#pragma unroll
        for (int off = 1; off < 64; off <<= 1) {
            int x = __shfl_up(s, off, 64);
            if (lane >= off) s += x;
        }
        if (lane == 63) wsum[w] = s;
        __syncthreads();
        if (w == 0) {
            int x = (lane < 16) ? wsum[lane] : 0;
#pragma unroll
            for (int off = 1; off < 16; off <<= 1) {
                int y = __shfl_up(x, off, 64);
                if (lane >= off) x += y;
            }
            if (lane < 16) wsum[lane] = x;
        }
        __syncthreads();
        int prefix = (w > 0) ? wsum[w - 1] : 0;
        int incl = s + prefix + carry;
        if (i < N) rowptr[i + 1] = incl;
        carry += wsum[15];
        __syncthreads();
    }
    if (t == 0) rowptr[0] = 0;
}

__global__ void scatter_kernel(const int* __restrict__ ei, int E, int Etot,
                               const int* __restrict__ rowptr, int* __restrict__ cursor,
                               int* __restrict__ csr) {
    int i = blockIdx.x * blockDim.x + threadIdx.x;
    int stride = gridDim.x * blockDim.x;
    for (int e = i; e < Etot; e += stride) {
        int s, d;
        if (e < E) { s = ei[e]; d = ei[E + e]; }
        else       { s = e - E; d = s; }
        int slot = atomicAdd(&cursor[d], 1);
        csr[rowptr[d] + slot] = s;
    }
}

// ---------------- GEMM: Y[N,M] = X[N,64] @ W[64,M], fp32 vector ALU ----------------

template <int M>
__global__ __launch_bounds__(256) void gemm64_kernel(const float* __restrict__ X,
                                                     const float* __restrict__ W,
                                                     float* __restrict__ Y, int N) {
    __shared__ float ws[64 * M];
    __shared__ float xs[64 * 64];
    int t = threadIdx.x;
    for (int i = t; i < 64 * M / 4; i += 256)
        ((float4*)ws)[i] = ((const float4*)W)[i];
    int r0 = blockIdx.x * 64;
    for (int i = t; i < 1024; i += 256) {
        int r = i >> 4, k4 = i & 15;
        int row = r0 + r;
        float4 v = (row < N) ? ((const float4*)X)[(size_t)row * 16 + k4]
                             : make_float4(0.f, 0.f, 0.f, 0.f);
        ((float4*)xs)[r * 16 + k4] = v;
    }
    __syncthreads();
    constexpr int RP = 64 / (256 / M);  // rows per thread: 16 (M=64) or 32 (M=128)
    int col = t % M;
    int tr = t / M;
    float acc[RP];
#pragma unroll
    for (int i = 0; i < RP; i++) acc[i] = 0.f;
#pragma unroll
    for (int k4 = 0; k4 < 16; k4++) {
        float w0 = ws[(4 * k4 + 0) * M + col];
        float w1 = ws[(4 * k4 + 1) * M + col];
        float w2 = ws[(4 * k4 + 2) * M + col];
        float w3 = ws[(4 * k4 + 3) * M + col];
#pragma unroll
        for (int i = 0; i < RP; i++) {
            float4 xv = ((const float4*)xs)[(tr * RP + i) * 16 + k4];
            acc[i] += xv.x * w0 + xv.y * w1 + xv.z * w2 + xv.w * w3;
        }
    }
#pragma unroll
    for (int i = 0; i < RP; i++) {
        int row = r0 + tr * RP + i;
        if (row < N) Y[(size_t)row * M + col] = acc[i];
    }
}

// ---------------- attention scores: a_src/a_dst [N,2] ----------------

template <int C>
__global__ __launch_bounds__(256) void att_kernel(const float* __restrict__ h,
                                                  const float* __restrict__ att_src,
                                                  const float* __restrict__ att_dst,
                                                  float* __restrict__ a_src,
                                                  float* __restrict__ a_dst, int N) {
    constexpr int F = 2 * C;
    constexpr int NP = 256 / F;
    int node = blockIdx.x * NP + threadIdx.x / F;
    int f = threadIdx.x % F;
    int hh = f / C;
    int c = f % C;
    if (node >= N) return;
    float hv = h[(size_t)node * F + f];
    float vs = hv * att_src[f];
    float vd = hv * att_dst[f];
#pragma unroll
    for (int m = C / 2; m > 0; m >>= 1) {
        vs += __shfl_xor(vs, m, C);
        vd += __shfl_xor(vd, m, C);
    }
    if (c == 0) {
        a_src[node * 2 + hh] = vs;
        a_dst[node * 2 + hh] = vd;
    }
}

// ---------------- aggregation, layer 1 (concat, H=2, C=32, F=64) ----------------

__global__ __launch_bounds__(256) void agg_concat_kernel(const float* __restrict__ h,
                                                         const float* __restrict__ a_src,
                                                         const float* __restrict__ a_dst,
                                                         const int* __restrict__ rowptr,
                                                         const int* __restrict__ csr,
                                                         const float* __restrict__ bias,
                                                         float* __restrict__ out, int N) {
    int node = blockIdx.x * 4 + (threadIdx.x >> 6);
    int f = threadIdx.x & 63;
    int hh = f >> 5;
    if (node >= N) return;
    int beg = rowptr[node], end = rowptr[node + 1];
    float ad = a_dst[node * 2 + hh];
    float m = -1e30f;
    for (int e = beg; e < end; ++e) {
        int s = csr[e];
        float a = lrelu(a_src[s * 2 + hh] + ad);
        m = fmaxf(m, a);
    }
    float denom = 0.f, acc = 0.f;
    for (int e = beg; e < end; ++e) {
        int s = csr[e];
        float a = lrelu(a_src[s * 2 + hh] + ad);
        float w = __expf(a - m);
        denom += w;
        acc += h[(size_t)s * 64 + f] * w;
    }
    out[(size_t)node * 64 + f] = acc / (denom + 1e-16f) + bias[f];
}

// ---------------- aggregation, layer 2 (mean over heads, H=2, C=64) ----------------

__global__ __launch_bounds__(256) void agg_mean_kernel(const float* __restrict__ h,
                                                       const float* __restrict__ a_src,
                                                       const float* __restrict__ a_dst,
                                                       const int* __restrict__ rowptr,
                                                       const int* __restrict__ csr,
                                                       const float* __restrict__ bias,
                                                       float* __restrict__ out, int N) {
    int node = blockIdx.x * 4 + (threadIdx.x >> 6);
    int c = threadIdx.x & 63;
    if (node >= N) return;
    int beg = rowptr[node], end = rowptr[node + 1];
    float ad0 = a_dst[node * 2 + 0];
    float ad1 = a_dst[node * 2 + 1];
    float m0 = -1e30f, m1 = -1e30f;
    for (int e = beg; e < end; ++e) {
        int s = csr[e];
        float a0 = lrelu(a_src[s * 2 + 0] + ad0);
        float a1 = lrelu(a_src[s * 2 + 1] + ad1);
        m0 = fmaxf(m0, a0);
        m1 = fmaxf(m1, a1);
    }
    float d0 = 0.f, d1 = 0.f, acc0 = 0.f, acc1 = 0.f;
    for (int e = beg; e < end; ++e) {
        int s = csr[e];
        float a0 = lrelu(a_src[s * 2 + 0] + ad0);
        float a1 = lrelu(a_src[s * 2 + 1] + ad1);
        float w0 = __expf(a0 - m0);
        float w1 = __expf(a1 - m1);
        d0 += w0;
        d1 += w1;
        acc0 += h[(size_t)s * 128 + c] * w0;
        acc1 += h[(size_t)s * 128 + 64 + c] * w1;
    }
    out[(size_t)node * 64 + c] =
        0.5f * (acc0 / (d0 + 1e-16f) + acc1 / (d1 + 1e-16f)) + bias[c];
}

// ---------------- launch ----------------

extern "C" void kernel_launch(void* const* d_in, const int* in_sizes, int n_in,
                              void* d_out, int out_size, void* d_ws, size_t ws_size,
                              hipStream_t stream) {
    const float* x        = (const float*)d_in[0];
    const int*   ei       = (const int*)d_in[1];
    const float* W1       = (const float*)d_in[2];
    const float* att_src1 = (const float*)d_in[3];
    const float* att_dst1 = (const float*)d_in[4];
    const float* b1       = (const float*)d_in[5];
    const float* W2       = (const float*)d_in[6];
    const float* att_src2 = (const float*)d_in[7];
    const float* att_dst2 = (const float*)d_in[8];
    const float* b2       = (const float*)d_in[9];
    float* out = (float*)d_out;

    const int N = in_sizes[0] / 64;
    const int E = in_sizes[1] / 2;
    const int Etot = E + N;

    // workspace carve-up (256B aligned)
    char* base = (char*)d_ws;
    size_t off = 0;
    auto alloc = [&](size_t bytes) -> char* {
        char* p = base + off;
        off = (off + bytes + 255) & ~(size_t)255;
        return p;
    };
    int*   deg     = (int*)alloc((size_t)N * 4);         // reused as cursor
    int*   rowptr  = (int*)alloc((size_t)(N + 1) * 4);
    int*   csr     = (int*)alloc((size_t)Etot * 4);
    float* h1      = (float*)alloc((size_t)N * 64 * 4);
    float* asrc1   = (float*)alloc((size_t)N * 2 * 4);
    float* adst1   = (float*)alloc((size_t)N * 2 * 4);
    float* out1    = (float*)alloc((size_t)N * 64 * 4);
    float* h2      = (float*)alloc((size_t)N * 128 * 4);
    float* asrc2   = (float*)alloc((size_t)N * 2 * 4);
    float* adst2   = (float*)alloc((size_t)N * 2 * 4);
    (void)ws_size; (void)n_in; (void)out_size;

    // CSR build (shared by both layers)
    hipMemsetAsync(deg, 0, (size_t)N * 4, stream);
    hist_kernel<<<(E + 255) / 256, 256, 0, stream>>>(ei + E, E, deg);
    scan_kernel<<<1, 1024, 0, stream>>>(deg, rowptr, N);
    hipMemsetAsync(deg, 0, (size_t)N * 4, stream);
    scatter_kernel<<<(Etot + 255) / 256, 256, 0, stream>>>(ei, E, Etot, rowptr, deg, csr);

    // layer 1
    gemm64_kernel<64><<<(N + 63) / 64, 256, 0, stream>>>(x, W1, h1, N);
    att_kernel<32><<<(N + 3) / 4, 256, 0, stream>>>(h1, att_src1, att_dst1, asrc1, adst1, N);
    agg_concat_kernel<<<(N + 3) / 4, 256, 0, stream>>>(h1, asrc1, adst1, rowptr, csr, b1, out1, N);

    // layer 2
    gemm64_kernel<128><<<(N + 63) / 64, 256, 0, stream>>>(out1, W2, h2, N);
    att_kernel<64><<<(N + 1) / 2, 256, 0, stream>>>(h2, att_src2, att_dst2, asrc2, adst2, N);
    agg_mean_kernel<<<(N + 3) / 4, 256, 0, stream>>>(h2, asrc2, adst2, rowptr, csr, b2, out, N);
}

// Round 2
// 1567.509 us; speedup vs baseline: 1.1030x; 1.1030x over previous
//
#include <hip/hip_runtime.h>

#define NEG_SLOPE 0.2f

__device__ __forceinline__ float lrelu(float a) { return a > 0.f ? a : NEG_SLOPE * a; }

// ---------------- CSR build ----------------

__global__ void hist_kernel(const int* __restrict__ dst, int E, int* __restrict__ deg) {
    int i = blockIdx.x * blockDim.x + threadIdx.x;
    int stride = gridDim.x * blockDim.x;
    for (int e = i; e < E; e += stride) atomicAdd(&deg[dst[e]], 1);
}

// exclusive rowptr over (deg[n] + 1 self-loop), single 1024-thread block, wave-level scan
__global__ __launch_bounds__(1024) void scan_kernel(const int* __restrict__ deg,
                                                    int* __restrict__ rowptr, int N) {
    __shared__ int wsum[16];
    int t = threadIdx.x, lane = t & 63, w = t >> 6;
    int carry = 0;
    for (int base = 0; base < N; base += 1024) {
        int i = base + t;
        int v = (i < N) ? deg[i] + 1 : 0;
        int s = v;
#pragma unroll
        for (int off = 1; off < 64; off <<= 1) {
            int x = __shfl_up(s, off, 64);
            if (lane >= off) s += x;
        }
        if (lane == 63) wsum[w] = s;
        __syncthreads();
        if (w == 0) {
            int x = (lane < 16) ? wsum[lane] : 0;
#pragma unroll
            for (int off = 1; off < 16; off <<= 1) {
                int y = __shfl_up(x, off, 64);
                if (lane >= off) x += y;
            }
            if (lane < 16) wsum[lane] = x;
        }
        __syncthreads();
        int prefix = (w > 0) ? wsum[w - 1] : 0;
        int incl = s + prefix + carry;
        if (i < N) rowptr[i + 1] = incl;
        carry += wsum[15];
        __syncthreads();
    }
    if (t == 0) rowptr[0] = 0;
}

__global__ void scatter_kernel(const int* __restrict__ ei, int E, int Etot,
                               const int* __restrict__ rowptr, int* __restrict__ cursor,
                               int* __restrict__ csr) {
    int i = blockIdx.x * blockDim.x + threadIdx.x;
    int stride = gridDim.x * blockDim.x;
    for (int e = i; e < Etot; e += stride) {
        int s, d;
        if (e < E) { s = ei[e]; d = ei[E + e]; }
        else       { s = e - E; d = s; }
        int slot = atomicAdd(&cursor[d], 1);
        csr[rowptr[d] + slot] = s;
    }
}

// ---------------- GEMM: Y[N,M] = X[N,64] @ W[64,M], fp32 vector ALU ----------------
// TR = row tile; RP = TR*M/256 = 16 rows/thread for both instantiations (no spill).

template <int M, int TR>
__global__ __launch_bounds__(256, 4) void gemm64_kernel(const float* __restrict__ X,
                                                        const float* __restrict__ W,
                                                        float* __restrict__ Y, int N) {
    constexpr int RP = TR * M / 256;  // 16
    __shared__ float ws[64 * M];
    __shared__ float xs[TR * 64];
    int t = threadIdx.x;
    for (int i = t; i < 64 * M / 4; i += 256)
        ((float4*)ws)[i] = ((const float4*)W)[i];
    int r0 = blockIdx.x * TR;
    for (int i = t; i < TR * 16; i += 256) {
        int r = i >> 4, k4 = i & 15;
        int row = r0 + r;
        float4 v = (row < N) ? ((const float4*)X)[(size_t)row * 16 + k4]
                             : make_float4(0.f, 0.f, 0.f, 0.f);
        ((float4*)xs)[r * 16 + k4] = v;
    }
    __syncthreads();
    int col = t % M;
    int rgrp = t / M;
    float acc[RP];
#pragma unroll
    for (int i = 0; i < RP; i++) acc[i] = 0.f;
#pragma unroll
    for (int k4 = 0; k4 < 16; k4++) {
        float w0 = ws[(4 * k4 + 0) * M + col];
        float w1 = ws[(4 * k4 + 1) * M + col];
        float w2 = ws[(4 * k4 + 2) * M + col];
        float w3 = ws[(4 * k4 + 3) * M + col];
#pragma unroll
        for (int i = 0; i < RP; i++) {
            float4 xv = ((const float4*)xs)[(rgrp * RP + i) * 16 + k4];
            acc[i] = fmaf(xv.x, w0, fmaf(xv.y, w1, fmaf(xv.z, w2, fmaf(xv.w, w3, acc[i]))));
        }
    }
#pragma unroll
    for (int i = 0; i < RP; i++) {
        int row = r0 + rgrp * RP + i;
        if (row < N) Y[(size_t)row * M + col] = acc[i];
    }
}

// ---------------- attention scores: a_src/a_dst [N,2] ----------------

template <int C>
__global__ __launch_bounds__(256) void att_kernel(const float* __restrict__ h,
                                                  const float* __restrict__ att_src,
                                                  const float* __restrict__ att_dst,
                                                  float* __restrict__ a_src,
                                                  float* __restrict__ a_dst, int N) {
    constexpr int F = 2 * C;
    constexpr int NP = 256 / F;
    int node = blockIdx.x * NP + threadIdx.x / F;
    int f = threadIdx.x % F;
    int hh = f / C;
    int c = f % C;
    if (node >= N) return;
    float hv = h[(size_t)node * F + f];
    float vs = hv * att_src[f];
    float vd = hv * att_dst[f];
#pragma unroll
    for (int m = C / 2; m > 0; m >>= 1) {
        vs += __shfl_xor(vs, m, C);
        vd += __shfl_xor(vd, m, C);
    }
    if (c == 0) {
        a_src[node * 2 + hh] = vs;
        a_dst[node * 2 + hh] = vd;
    }
}

// ---------------- aggregation, layer 1 (concat, H=2, C=32, F=64) ----------------

__global__ __launch_bounds__(256) void agg_concat_kernel(const float* __restrict__ h,
                                                         const float* __restrict__ a_src,
                                                         const float* __restrict__ a_dst,
                                                         const int* __restrict__ rowptr,
                                                         const int* __restrict__ csr,
                                                         const float* __restrict__ bias,
                                                         float* __restrict__ out, int N) {
    int node = blockIdx.x * 4 + (threadIdx.x >> 6);
    int f = threadIdx.x & 63;
    int hh = f >> 5;
    if (node >= N) return;
    int beg = rowptr[node], end = rowptr[node + 1];
    float ad = a_dst[node * 2 + hh];
    float m = -1e30f;
    for (int e = beg; e < end; ++e) {
        int s = csr[e];
        float a = lrelu(a_src[s * 2 + hh] + ad);
        m = fmaxf(m, a);
    }
    float denom = 0.f, acc = 0.f;
    for (int e = beg; e < end; ++e) {
        int s = csr[e];
        float a = lrelu(a_src[s * 2 + hh] + ad);
        float w = __expf(a - m);
        denom += w;
        acc += h[(size_t)s * 64 + f] * w;
    }
    out[(size_t)node * 64 + f] = acc / (denom + 1e-16f) + bias[f];
}

// ---------------- aggregation, layer 2 (mean over heads, H=2, C=64) ----------------

__global__ __launch_bounds__(256) void agg_mean_kernel(const float* __restrict__ h,
                                                       const float* __restrict__ a_src,
                                                       const float* __restrict__ a_dst,
                                                       const int* __restrict__ rowptr,
                                                       const int* __restrict__ csr,
                                                       const float* __restrict__ bias,
                                                       float* __restrict__ out, int N) {
    int node = blockIdx.x * 4 + (threadIdx.x >> 6);
    int c = threadIdx.x & 63;
    if (node >= N) return;
    int beg = rowptr[node], end = rowptr[node + 1];
    float ad0 = a_dst[node * 2 + 0];
    float ad1 = a_dst[node * 2 + 1];
    float m0 = -1e30f, m1 = -1e30f;
    for (int e = beg; e < end; ++e) {
        int s = csr[e];
        float a0 = lrelu(a_src[s * 2 + 0] + ad0);
        float a1 = lrelu(a_src[s * 2 + 1] + ad1);
        m0 = fmaxf(m0, a0);
        m1 = fmaxf(m1, a1);
    }
    float d0 = 0.f, d1 = 0.f, acc0 = 0.f, acc1 = 0.f;
    for (int e = beg; e < end; ++e) {
        int s = csr[e];
        float a0 = lrelu(a_src[s * 2 + 0] + ad0);
        float a1 = lrelu(a_src[s * 2 + 1] + ad1);
        float w0 = __expf(a0 - m0);
        float w1 = __expf(a1 - m1);
        d0 += w0;
        d1 += w1;
        acc0 += h[(size_t)s * 128 + c] * w0;
        acc1 += h[(size_t)s * 128 + 64 + c] * w1;
    }
    out[(size_t)node * 64 + c] =
        0.5f * (acc0 / (d0 + 1e-16f) + acc1 / (d1 + 1e-16f)) + bias[c];
}

// ---------------- launch ----------------

extern "C" void kernel_launch(void* const* d_in, const int* in_sizes, int n_in,
                              void* d_out, int out_size, void* d_ws, size_t ws_size,
                              hipStream_t stream) {
    const float* x        = (const float*)d_in[0];
    const int*   ei       = (const int*)d_in[1];
    const float* W1       = (const float*)d_in[2];
    const float* att_src1 = (const float*)d_in[3];
    const float* att_dst1 = (const float*)d_in[4];
    const float* b1       = (const float*)d_in[5];
    const float* W2       = (const float*)d_in[6];
    const float* att_src2 = (const float*)d_in[7];
    const float* att_dst2 = (const float*)d_in[8];
    const float* b2       = (const float*)d_in[9];
    float* out = (float*)d_out;

    const int N = in_sizes[0] / 64;
    const int E = in_sizes[1] / 2;
    const int Etot = E + N;

    // workspace carve-up (256B aligned)
    char* base = (char*)d_ws;
    size_t off = 0;
    auto alloc = [&](size_t bytes) -> char* {
        char* p = base + off;
        off = (off + bytes + 255) & ~(size_t)255;
        return p;
    };
    int*   deg     = (int*)alloc((size_t)N * 4);         // reused as cursor
    int*   rowptr  = (int*)alloc((size_t)(N + 1) * 4);
    int*   csr     = (int*)alloc((size_t)Etot * 4);
    float* h1      = (float*)alloc((size_t)N * 64 * 4);
    float* asrc1   = (float*)alloc((size_t)N * 2 * 4);
    float* adst1   = (float*)alloc((size_t)N * 2 * 4);
    float* out1    = (float*)alloc((size_t)N * 64 * 4);
    float* h2      = (float*)alloc((size_t)N * 128 * 4);
    float* asrc2   = (float*)alloc((size_t)N * 2 * 4);
    float* adst2   = (float*)alloc((size_t)N * 2 * 4);
    (void)ws_size; (void)n_in; (void)out_size;

    // CSR build (shared by both layers)
    hipMemsetAsync(deg, 0, (size_t)N * 4, stream);
    hist_kernel<<<(E + 255) / 256, 256, 0, stream>>>(ei + E, E, deg);
    scan_kernel<<<1, 1024, 0, stream>>>(deg, rowptr, N);
    hipMemsetAsync(deg, 0, (size_t)N * 4, stream);
    scatter_kernel<<<(Etot + 255) / 256, 256, 0, stream>>>(ei, E, Etot, rowptr, deg, csr);

    // layer 1
    gemm64_kernel<64, 64><<<(N + 63) / 64, 256, 0, stream>>>(x, W1, h1, N);
    att_kernel<32><<<(N + 3) / 4, 256, 0, stream>>>(h1, att_src1, att_dst1, asrc1, adst1, N);
    agg_concat_kernel<<<(N + 3) / 4, 256, 0, stream>>>(h1, asrc1, adst1, rowptr, csr, b1, out1, N);

    // layer 2
    gemm64_kernel<128, 32><<<(N + 31) / 32, 256, 0, stream>>>(out1, W2, h2, N);
    att_kernel<64><<<(N + 1) / 2, 256, 0, stream>>>(h2, att_src2, att_dst2, asrc2, adst2, N);
    agg_mean_kernel<<<(N + 3) / 4, 256, 0, stream>>>(h2, asrc2, adst2, rowptr, csr, b2, out, N);
}

// Round 3
// 515.514 us; speedup vs baseline: 3.3537x; 3.0407x over previous
//
#include <hip/hip_runtime.h>

#define NEG_SLOPE 0.2f

__device__ __forceinline__ float lrelu(float a) { return a > 0.f ? a : NEG_SLOPE * a; }

// ---------------- CSR build ----------------

__global__ void hist_kernel(const int* __restrict__ dst, int E, int* __restrict__ deg) {
    int i = blockIdx.x * blockDim.x + threadIdx.x;
    int stride = gridDim.x * blockDim.x;
    for (int e = i; e < E; e += stride) atomicAdd(&deg[dst[e]], 1);
}

// exclusive rowptr over (deg[n] + 1 self-loop), single 1024-thread block, wave-level scan
__global__ __launch_bounds__(1024) void scan_kernel(const int* __restrict__ deg,
                                                    int* __restrict__ rowptr, int N) {
    __shared__ int wsum[16];
    int t = threadIdx.x, lane = t & 63, w = t >> 6;
    int carry = 0;
    for (int base = 0; base < N; base += 1024) {
        int i = base + t;
        int v = (i < N) ? deg[i] + 1 : 0;
        int s = v;
#pragma unroll
        for (int off = 1; off < 64; off <<= 1) {
            int x = __shfl_up(s, off, 64);
            if (lane >= off) s += x;
        }
        if (lane == 63) wsum[w] = s;
        __syncthreads();
        if (w == 0) {
            int x = (lane < 16) ? wsum[lane] : 0;
#pragma unroll
            for (int off = 1; off < 16; off <<= 1) {
                int y = __shfl_up(x, off, 64);
                if (lane >= off) x += y;
            }
            if (lane < 16) wsum[lane] = x;
        }
        __syncthreads();
        int prefix = (w > 0) ? wsum[w - 1] : 0;
        int incl = s + prefix + carry;
        if (i < N) rowptr[i + 1] = incl;
        carry += wsum[15];
        __syncthreads();
    }
    if (t == 0) rowptr[0] = 0;
}

__global__ void scatter_kernel(const int* __restrict__ ei, int E, int Etot,
                               const int* __restrict__ rowptr, int* __restrict__ cursor,
                               int* __restrict__ csr) {
    int i = blockIdx.x * blockDim.x + threadIdx.x;
    int stride = gridDim.x * blockDim.x;
    for (int e = i; e < Etot; e += stride) {
        int s, d;
        if (e < E) { s = ei[e]; d = ei[E + e]; }
        else       { s = e - E; d = s; }
        int slot = atomicAdd(&cursor[d], 1);
        csr[rowptr[d] + slot] = s;
    }
}

// ---------------- GEMM: Y[N,M] = X[N,64] @ W[64,M], fp32 vector ALU ----------------
// Spill-proof: each thread owns 2 rows x 4 cols -> float4 acc[2] (~24 VGPR total).
// xs rows padded to 68 floats so per-wave row addresses hit distinct banks.

template <int M>
__global__ __launch_bounds__(256) void gemm64_kernel(const float* __restrict__ X,
                                                     const float* __restrict__ W,
                                                     float* __restrict__ Y, int N) {
    constexpr int CG = M / 4;             // float4 col-groups: 16 (M=64) or 32 (M=128)
    constexpr int RB = (256 / CG) * 2;    // rows per block: 32 (M=64) or 16 (M=128)
    __shared__ float4 ws[64 * CG];        // W[k][cg]
    __shared__ float  xs[RB][68];         // X tile, padded
    int t = threadIdx.x;
    for (int i = t; i < 64 * CG; i += 256) ws[i] = ((const float4*)W)[i];
    int r0 = blockIdx.x * RB;
    for (int i = t; i < RB * 16; i += 256) {
        int r = i >> 4, k4 = i & 15;
        int row = r0 + r;
        float4 v = (row < N) ? ((const float4*)X)[(size_t)row * 16 + k4]
                             : make_float4(0.f, 0.f, 0.f, 0.f);
        ((float4*)&xs[r][0])[k4] = v;
    }
    __syncthreads();
    int c = t % CG;
    int rl = (t / CG) * 2;
    float4 a0 = make_float4(0.f, 0.f, 0.f, 0.f);
    float4 a1 = make_float4(0.f, 0.f, 0.f, 0.f);
#pragma unroll
    for (int k = 0; k < 64; k++) {
        float4 w = ws[k * CG + c];
        float x0 = xs[rl][k];
        float x1 = xs[rl + 1][k];
        a0.x = fmaf(x0, w.x, a0.x); a0.y = fmaf(x0, w.y, a0.y);
        a0.z = fmaf(x0, w.z, a0.z); a0.w = fmaf(x0, w.w, a0.w);
        a1.x = fmaf(x1, w.x, a1.x); a1.y = fmaf(x1, w.y, a1.y);
        a1.z = fmaf(x1, w.z, a1.z); a1.w = fmaf(x1, w.w, a1.w);
    }
    int row0 = r0 + rl;
    if (row0 < N)     ((float4*)Y)[(size_t)row0 * CG + c] = a0;
    if (row0 + 1 < N) ((float4*)Y)[(size_t)(row0 + 1) * CG + c] = a1;
}

// ---------------- attention scores: a_src/a_dst [N,2] ----------------

template <int C>
__global__ __launch_bounds__(256) void att_kernel(const float* __restrict__ h,
                                                  const float* __restrict__ att_src,
                                                  const float* __restrict__ att_dst,
                                                  float* __restrict__ a_src,
                                                  float* __restrict__ a_dst, int N) {
    constexpr int F = 2 * C;
    constexpr int NP = 256 / F;
    int node = blockIdx.x * NP + threadIdx.x / F;
    int f = threadIdx.x % F;
    int hh = f / C;
    int c = f % C;
    if (node >= N) return;
    float hv = h[(size_t)node * F + f];
    float vs = hv * att_src[f];
    float vd = hv * att_dst[f];
#pragma unroll
    for (int m = C / 2; m > 0; m >>= 1) {
        vs += __shfl_xor(vs, m, C);
        vd += __shfl_xor(vd, m, C);
    }
    if (c == 0) {
        a_src[node * 2 + hh] = vs;
        a_dst[node * 2 + hh] = vd;
    }
}

// ---------------- aggregation, layer 1 (concat, H=2, C=32, F=64) ----------------

__global__ __launch_bounds__(256) void agg_concat_kernel(const float* __restrict__ h,
                                                         const float* __restrict__ a_src,
                                                         const float* __restrict__ a_dst,
                                                         const int* __restrict__ rowptr,
                                                         const int* __restrict__ csr,
                                                         const float* __restrict__ bias,
                                                         float* __restrict__ out, int N) {
    int node = blockIdx.x * 4 + (threadIdx.x >> 6);
    int f = threadIdx.x & 63;
    int hh = f >> 5;
    if (node >= N) return;
    int beg = rowptr[node], end = rowptr[node + 1];
    float ad = a_dst[node * 2 + hh];
    float m = -1e30f;
    for (int e = beg; e < end; ++e) {
        int s = csr[e];
        float a = lrelu(a_src[s * 2 + hh] + ad);
        m = fmaxf(m, a);
    }
    float denom = 0.f, acc = 0.f;
    for (int e = beg; e < end; ++e) {
        int s = csr[e];
        float a = lrelu(a_src[s * 2 + hh] + ad);
        float w = __expf(a - m);
        denom += w;
        acc += h[(size_t)s * 64 + f] * w;
    }
    out[(size_t)node * 64 + f] = acc / (denom + 1e-16f) + bias[f];
}

// ---------------- aggregation, layer 2 (mean over heads, H=2, C=64) ----------------

__global__ __launch_bounds__(256) void agg_mean_kernel(const float* __restrict__ h,
                                                       const float* __restrict__ a_src,
                                                       const float* __restrict__ a_dst,
                                                       const int* __restrict__ rowptr,
                                                       const int* __restrict__ csr,
                                                       const float* __restrict__ bias,
                                                       float* __restrict__ out, int N) {
    int node = blockIdx.x * 4 + (threadIdx.x >> 6);
    int c = threadIdx.x & 63;
    if (node >= N) return;
    int beg = rowptr[node], end = rowptr[node + 1];
    float ad0 = a_dst[node * 2 + 0];
    float ad1 = a_dst[node * 2 + 1];
    float m0 = -1e30f, m1 = -1e30f;
    for (int e = beg; e < end; ++e) {
        int s = csr[e];
        float a0 = lrelu(a_src[s * 2 + 0] + ad0);
        float a1 = lrelu(a_src[s * 2 + 1] + ad1);
        m0 = fmaxf(m0, a0);
        m1 = fmaxf(m1, a1);
    }
    float d0 = 0.f, d1 = 0.f, acc0 = 0.f, acc1 = 0.f;
    for (int e = beg; e < end; ++e) {
        int s = csr[e];
        float a0 = lrelu(a_src[s * 2 + 0] + ad0);
        float a1 = lrelu(a_src[s * 2 + 1] + ad1);
        float w0 = __expf(a0 - m0);
        float w1 = __expf(a1 - m1);
        d0 += w0;
        d1 += w1;
        acc0 += h[(size_t)s * 128 + c] * w0;
        acc1 += h[(size_t)s * 128 + 64 + c] * w1;
    }
    out[(size_t)node * 64 + c] =
        0.5f * (acc0 / (d0 + 1e-16f) + acc1 / (d1 + 1e-16f)) + bias[c];
}

// ---------------- launch ----------------

extern "C" void kernel_launch(void* const* d_in, const int* in_sizes, int n_in,
                              void* d_out, int out_size, void* d_ws, size_t ws_size,
                              hipStream_t stream) {
    const float* x        = (const float*)d_in[0];
    const int*   ei       = (const int*)d_in[1];
    const float* W1       = (const float*)d_in[2];
    const float* att_src1 = (const float*)d_in[3];
    const float* att_dst1 = (const float*)d_in[4];
    const float* b1       = (const float*)d_in[5];
    const float* W2       = (const float*)d_in[6];
    const float* att_src2 = (const float*)d_in[7];
    const float* att_dst2 = (const float*)d_in[8];
    const float* b2       = (const float*)d_in[9];
    float* out = (float*)d_out;

    const int N = in_sizes[0] / 64;
    const int E = in_sizes[1] / 2;
    const int Etot = E + N;

    // workspace carve-up (256B aligned)
    char* base = (char*)d_ws;
    size_t off = 0;
    auto alloc = [&](size_t bytes) -> char* {
        char* p = base + off;
        off = (off + bytes + 255) & ~(size_t)255;
        return p;
    };
    int*   deg     = (int*)alloc((size_t)N * 4);         // reused as cursor
    int*   rowptr  = (int*)alloc((size_t)(N + 1) * 4);
    int*   csr     = (int*)alloc((size_t)Etot * 4);
    float* h1      = (float*)alloc((size_t)N * 64 * 4);
    float* asrc1   = (float*)alloc((size_t)N * 2 * 4);
    float* adst1   = (float*)alloc((size_t)N * 2 * 4);
    float* out1    = (float*)alloc((size_t)N * 64 * 4);
    float* h2      = (float*)alloc((size_t)N * 128 * 4);
    float* asrc2   = (float*)alloc((size_t)N * 2 * 4);
    float* adst2   = (float*)alloc((size_t)N * 2 * 4);
    (void)ws_size; (void)n_in; (void)out_size;

    // CSR build (shared by both layers)
    hipMemsetAsync(deg, 0, (size_t)N * 4, stream);
    hist_kernel<<<(E + 255) / 256, 256, 0, stream>>>(ei + E, E, deg);
    scan_kernel<<<1, 1024, 0, stream>>>(deg, rowptr, N);
    hipMemsetAsync(deg, 0, (size_t)N * 4, stream);
    scatter_kernel<<<(Etot + 255) / 256, 256, 0, stream>>>(ei, E, Etot, rowptr, deg, csr);

    // layer 1
    gemm64_kernel<64><<<(N + 31) / 32, 256, 0, stream>>>(x, W1, h1, N);
    att_kernel<32><<<(N + 3) / 4, 256, 0, stream>>>(h1, att_src1, att_dst1, asrc1, adst1, N);
    agg_concat_kernel<<<(N + 3) / 4, 256, 0, stream>>>(h1, asrc1, adst1, rowptr, csr, b1, out1, N);

    // layer 2
    gemm64_kernel<128><<<(N + 15) / 16, 256, 0, stream>>>(out1, W2, h2, N);
    att_kernel<64><<<(N + 1) / 2, 256, 0, stream>>>(h2, att_src2, att_dst2, asrc2, adst2, N);
    agg_mean_kernel<<<(N + 3) / 4, 256, 0, stream>>>(h2, asrc2, adst2, rowptr, csr, b2, out, N);
}

// Round 4
// 347.932 us; speedup vs baseline: 4.9691x; 1.4817x over previous
//
#include <hip/hip_runtime.h>

#define NEG_SLOPE 0.2f

__device__ __forceinline__ float lrelu(float a) { return a > 0.f ? a : NEG_SLOPE * a; }

// ---------------- CSR build ----------------

__global__ void hist_kernel(const int* __restrict__ dst, int E, int* __restrict__ deg) {
    int i = blockIdx.x * blockDim.x + threadIdx.x;
    int stride = gridDim.x * blockDim.x;
    for (int e = i; e < E; e += stride) atomicAdd(&deg[dst[e]], 1);
}

// exclusive rowptr over (deg[n] + 1 self-loop), single 1024-thread block, wave-level scan
__global__ __launch_bounds__(1024) void scan_kernel(const int* __restrict__ deg,
                                                    int* __restrict__ rowptr, int N) {
    __shared__ int wsum[16];
    int t = threadIdx.x, lane = t & 63, w = t >> 6;
    int carry = 0;
    for (int base = 0; base < N; base += 1024) {
        int i = base + t;
        int v = (i < N) ? deg[i] + 1 : 0;
        int s = v;
#pragma unroll
        for (int off = 1; off < 64; off <<= 1) {
            int x = __shfl_up(s, off, 64);
            if (lane >= off) s += x;
        }
        if (lane == 63) wsum[w] = s;
        __syncthreads();
        if (w == 0) {
            int x = (lane < 16) ? wsum[lane] : 0;
#pragma unroll
            for (int off = 1; off < 16; off <<= 1) {
                int y = __shfl_up(x, off, 64);
                if (lane >= off) x += y;
            }
            if (lane < 16) wsum[lane] = x;
        }
        __syncthreads();
        int prefix = (w > 0) ? wsum[w - 1] : 0;
        int incl = s + prefix + carry;
        if (i < N) rowptr[i + 1] = incl;
        carry += wsum[15];
        __syncthreads();
    }
    if (t == 0) rowptr[0] = 0;
}

__global__ void scatter_kernel(const int* __restrict__ ei, int E, int Etot,
                               const int* __restrict__ rowptr, int* __restrict__ cursor,
                               int* __restrict__ csr) {
    int i = blockIdx.x * blockDim.x + threadIdx.x;
    int stride = gridDim.x * blockDim.x;
    for (int e = i; e < Etot; e += stride) {
        int s, d;
        if (e < E) { s = ei[e]; d = ei[E + e]; }
        else       { s = e - E; d = s; }
        int slot = atomicAdd(&cursor[d], 1);
        csr[rowptr[d] + slot] = s;
    }
}

// ---------------- GEMM: Y[N,M] = X[N,64] @ W[64,M], fp32 vector ALU ----------------

template <int M>
__global__ __launch_bounds__(256) void gemm64_kernel(const float* __restrict__ X,
                                                     const float* __restrict__ W,
                                                     float* __restrict__ Y, int N) {
    constexpr int CG = M / 4;             // float4 col-groups
    constexpr int RB = (256 / CG) * 2;    // rows per block
    __shared__ float4 ws[64 * CG];
    __shared__ float  xs[RB][68];
    int t = threadIdx.x;
    for (int i = t; i < 64 * CG; i += 256) ws[i] = ((const float4*)W)[i];
    int r0 = blockIdx.x * RB;
    for (int i = t; i < RB * 16; i += 256) {
        int r = i >> 4, k4 = i & 15;
        int row = r0 + r;
        float4 v = (row < N) ? ((const float4*)X)[(size_t)row * 16 + k4]
                             : make_float4(0.f, 0.f, 0.f, 0.f);
        ((float4*)&xs[r][0])[k4] = v;
    }
    __syncthreads();
    int c = t % CG;
    int rl = (t / CG) * 2;
    float4 a0 = make_float4(0.f, 0.f, 0.f, 0.f);
    float4 a1 = make_float4(0.f, 0.f, 0.f, 0.f);
#pragma unroll
    for (int k = 0; k < 64; k++) {
        float4 w = ws[k * CG + c];
        float x0 = xs[rl][k];
        float x1 = xs[rl + 1][k];
        a0.x = fmaf(x0, w.x, a0.x); a0.y = fmaf(x0, w.y, a0.y);
        a0.z = fmaf(x0, w.z, a0.z); a0.w = fmaf(x0, w.w, a0.w);
        a1.x = fmaf(x1, w.x, a1.x); a1.y = fmaf(x1, w.y, a1.y);
        a1.z = fmaf(x1, w.z, a1.z); a1.w = fmaf(x1, w.w, a1.w);
    }
    int row0 = r0 + rl;
    if (row0 < N)     ((float4*)Y)[(size_t)row0 * CG + c] = a0;
    if (row0 + 1 < N) ((float4*)Y)[(size_t)(row0 + 1) * CG + c] = a1;
}

// ---------------- attention scores: a_src/a_dst [N,2] interleaved ----------------

template <int C>
__global__ __launch_bounds__(256) void att_kernel(const float* __restrict__ h,
                                                  const float* __restrict__ att_src,
                                                  const float* __restrict__ att_dst,
                                                  float* __restrict__ a_src,
                                                  float* __restrict__ a_dst, int N) {
    constexpr int F = 2 * C;
    constexpr int NP = 256 / F;
    int node = blockIdx.x * NP + threadIdx.x / F;
    int f = threadIdx.x % F;
    int hh = f / C;
    int c = f % C;
    if (node >= N) return;
    float hv = h[(size_t)node * F + f];
    float vs = hv * att_src[f];
    float vd = hv * att_dst[f];
#pragma unroll
    for (int m = C / 2; m > 0; m >>= 1) {
        vs += __shfl_xor(vs, m, C);
        vd += __shfl_xor(vd, m, C);
    }
    if (c == 0) {
        a_src[node * 2 + hh] = vs;
        a_dst[node * 2 + hh] = vd;
    }
}

// ---------------- edge softmax: normalized weights in CSR order ----------------
// one wave per node, lane = edge; both heads per lane.

__global__ __launch_bounds__(256) void edge_softmax_kernel(const float* __restrict__ a_src,
                                                           const float* __restrict__ a_dst,
                                                           const int* __restrict__ rowptr,
                                                           const int* __restrict__ csr,
                                                           float* __restrict__ wnorm,
                                                           int N) {
    int node = blockIdx.x * 4 + (threadIdx.x >> 6);
    int lane = threadIdx.x & 63;
    if (node >= N) return;
    int beg = rowptr[node], end = rowptr[node + 1];
    int deg = end - beg;
    float ad0 = a_dst[node * 2 + 0];
    float ad1 = a_dst[node * 2 + 1];
    if (deg <= 64) {
        float a0 = -1e30f, a1 = -1e30f;
        int e = beg + lane;
        if (lane < deg) {
            int s = csr[e];
            float2 as = ((const float2*)a_src)[s];
            a0 = lrelu(as.x + ad0);
            a1 = lrelu(as.y + ad1);
        }
        float m0 = a0, m1 = a1;
#pragma unroll
        for (int off = 32; off; off >>= 1) {
            m0 = fmaxf(m0, __shfl_xor(m0, off, 64));
            m1 = fmaxf(m1, __shfl_xor(m1, off, 64));
        }
        float w0 = (lane < deg) ? __expf(a0 - m0) : 0.f;
        float w1 = (lane < deg) ? __expf(a1 - m1) : 0.f;
        float d0 = w0, d1 = w1;
#pragma unroll
        for (int off = 32; off; off >>= 1) {
            d0 += __shfl_xor(d0, off, 64);
            d1 += __shfl_xor(d1, off, 64);
        }
        if (lane < deg)
            ((float2*)wnorm)[e] = make_float2(w0 / (d0 + 1e-16f), w1 / (d1 + 1e-16f));
    } else {
        float m0 = -1e30f, m1 = -1e30f;
        for (int i = lane; i < deg; i += 64) {
            int s = csr[beg + i];
            float2 as = ((const float2*)a_src)[s];
            m0 = fmaxf(m0, lrelu(as.x + ad0));
            m1 = fmaxf(m1, lrelu(as.y + ad1));
        }
#pragma unroll
        for (int off = 32; off; off >>= 1) {
            m0 = fmaxf(m0, __shfl_xor(m0, off, 64));
            m1 = fmaxf(m1, __shfl_xor(m1, off, 64));
        }
        float d0 = 0.f, d1 = 0.f;
        for (int i = lane; i < deg; i += 64) {
            int s = csr[beg + i];
            float2 as = ((const float2*)a_src)[s];
            d0 += __expf(lrelu(as.x + ad0) - m0);
            d1 += __expf(lrelu(as.y + ad1) - m1);
        }
#pragma unroll
        for (int off = 32; off; off >>= 1) {
            d0 += __shfl_xor(d0, off, 64);
            d1 += __shfl_xor(d1, off, 64);
        }
        float inv0 = 1.f / (d0 + 1e-16f), inv1 = 1.f / (d1 + 1e-16f);
        for (int i = lane; i < deg; i += 64) {
            int s = csr[beg + i];
            float2 as = ((const float2*)a_src)[s];
            ((float2*)wnorm)[beg + i] =
                make_float2(__expf(lrelu(as.x + ad0) - m0) * inv0,
                            __expf(lrelu(as.y + ad1) - m1) * inv1);
        }
    }
}

// ---------------- aggregation, layer 1 (concat; h row = 16 float4, head = q>=8) ----

__global__ __launch_bounds__(256) void agg_concat_kernel(const float* __restrict__ h,
                                                         const float* __restrict__ wnorm,
                                                         const int* __restrict__ rowptr,
                                                         const int* __restrict__ csr,
                                                         const float* __restrict__ bias,
                                                         float* __restrict__ out, int N) {
    int node = blockIdx.x * 4 + (threadIdx.x >> 6);
    if (node >= N) return;
    int lane = threadIdx.x & 63;
    int g = lane >> 4, q = lane & 15;
    int beg = rowptr[node], end = rowptr[node + 1];
    const float4* h4 = (const float4*)h;
    float4 acc = make_float4(0.f, 0.f, 0.f, 0.f);
    for (int e = beg + g; e < end; e += 4) {
        int s = csr[e];
        float2 wp = ((const float2*)wnorm)[e];
        float w = (q < 8) ? wp.x : wp.y;
        float4 v = h4[(size_t)s * 16 + q];
        acc.x = fmaf(v.x, w, acc.x);
        acc.y = fmaf(v.y, w, acc.y);
        acc.z = fmaf(v.z, w, acc.z);
        acc.w = fmaf(v.w, w, acc.w);
    }
#pragma unroll
    for (int off = 16; off <= 32; off <<= 1) {
        acc.x += __shfl_xor(acc.x, off, 64);
        acc.y += __shfl_xor(acc.y, off, 64);
        acc.z += __shfl_xor(acc.z, off, 64);
        acc.w += __shfl_xor(acc.w, off, 64);
    }
    if (g == 0) {
        float4 b = ((const float4*)bias)[q];
        acc.x += b.x; acc.y += b.y; acc.z += b.z; acc.w += b.w;
        ((float4*)out)[(size_t)node * 16 + q] = acc;
    }
}

// ---------------- aggregation, layer 2 (mean; h row = 32 float4, heads 0-15/16-31) --

__global__ __launch_bounds__(256) void agg_mean_kernel(const float* __restrict__ h,
                                                       const float* __restrict__ wnorm,
                                                       const int* __restrict__ rowptr,
                                                       const int* __restrict__ csr,
                                                       const float* __restrict__ bias,
                                                       float* __restrict__ out, int N) {
    int node = blockIdx.x * 4 + (threadIdx.x >> 6);
    if (node >= N) return;
    int lane = threadIdx.x & 63;
    int g = lane >> 4, q = lane & 15;
    int beg = rowptr[node], end = rowptr[node + 1];
    const float4* h4 = (const float4*)h;
    float4 acc0 = make_float4(0.f, 0.f, 0.f, 0.f);
    float4 acc1 = make_float4(0.f, 0.f, 0.f, 0.f);
    for (int e = beg + g; e < end; e += 4) {
        int s = csr[e];
        float2 wp = ((const float2*)wnorm)[e];
        float4 v0 = h4[(size_t)s * 32 + q];
        float4 v1 = h4[(size_t)s * 32 + 16 + q];
        acc0.x = fmaf(v0.x, wp.x, acc0.x);
        acc0.y = fmaf(v0.y, wp.x, acc0.y);
        acc0.z = fmaf(v0.z, wp.x, acc0.z);
        acc0.w = fmaf(v0.w, wp.x, acc0.w);
        acc1.x = fmaf(v1.x, wp.y, acc1.x);
        acc1.y = fmaf(v1.y, wp.y, acc1.y);
        acc1.z = fmaf(v1.z, wp.y, acc1.z);
        acc1.w = fmaf(v1.w, wp.y, acc1.w);
    }
#pragma unroll
    for (int off = 16; off <= 32; off <<= 1) {
        acc0.x += __shfl_xor(acc0.x, off, 64);
        acc0.y += __shfl_xor(acc0.y, off, 64);
        acc0.z += __shfl_xor(acc0.z, off, 64);
        acc0.w += __shfl_xor(acc0.w, off, 64);
        acc1.x += __shfl_xor(acc1.x, off, 64);
        acc1.y += __shfl_xor(acc1.y, off, 64);
        acc1.z += __shfl_xor(acc1.z, off, 64);
        acc1.w += __shfl_xor(acc1.w, off, 64);
    }
    if (g == 0) {
        float4 b = ((const float4*)bias)[q];
        float4 o;
        o.x = 0.5f * (acc0.x + acc1.x) + b.x;
        o.y = 0.5f * (acc0.y + acc1.y) + b.y;
        o.z = 0.5f * (acc0.z + acc1.z) + b.z;
        o.w = 0.5f * (acc0.w + acc1.w) + b.w;
        ((float4*)out)[(size_t)node * 16 + q] = o;
    }
}

// ---------------- launch ----------------

extern "C" void kernel_launch(void* const* d_in, const int* in_sizes, int n_in,
                              void* d_out, int out_size, void* d_ws, size_t ws_size,
                              hipStream_t stream) {
    const float* x        = (const float*)d_in[0];
    const int*   ei       = (const int*)d_in[1];
    const float* W1       = (const float*)d_in[2];
    const float* att_src1 = (const float*)d_in[3];
    const float* att_dst1 = (const float*)d_in[4];
    const float* b1       = (const float*)d_in[5];
    const float* W2       = (const float*)d_in[6];
    const float* att_src2 = (const float*)d_in[7];
    const float* att_dst2 = (const float*)d_in[8];
    const float* b2       = (const float*)d_in[9];
    float* out = (float*)d_out;

    const int N = in_sizes[0] / 64;
    const int E = in_sizes[1] / 2;
    const int Etot = E + N;

    // workspace carve-up (256B aligned)
    char* base = (char*)d_ws;
    size_t off = 0;
    auto alloc = [&](size_t bytes) -> char* {
        char* p = base + off;
        off = (off + bytes + 255) & ~(size_t)255;
        return p;
    };
    int*   deg     = (int*)alloc((size_t)N * 4);         // reused as cursor
    int*   rowptr  = (int*)alloc((size_t)(N + 1) * 4);
    int*   csr     = (int*)alloc((size_t)Etot * 4);
    float* h1      = (float*)alloc((size_t)N * 64 * 4);
    float* asrc1   = (float*)alloc((size_t)N * 2 * 4);
    float* adst1   = (float*)alloc((size_t)N * 2 * 4);
    float* out1    = (float*)alloc((size_t)N * 64 * 4);
    float* h2      = (float*)alloc((size_t)N * 128 * 4);
    float* asrc2   = (float*)alloc((size_t)N * 2 * 4);
    float* adst2   = (float*)alloc((size_t)N * 2 * 4);
    float* wnorm   = (float*)alloc((size_t)Etot * 2 * 4); // reused by both layers
    (void)ws_size; (void)n_in; (void)out_size;

    // CSR build (shared by both layers)
    hipMemsetAsync(deg, 0, (size_t)N * 4, stream);
    hist_kernel<<<(E + 255) / 256, 256, 0, stream>>>(ei + E, E, deg);
    scan_kernel<<<1, 1024, 0, stream>>>(deg, rowptr, N);
    hipMemsetAsync(deg, 0, (size_t)N * 4, stream);
    scatter_kernel<<<(Etot + 255) / 256, 256, 0, stream>>>(ei, E, Etot, rowptr, deg, csr);

    int nb4 = (N + 3) / 4;

    // layer 1
    gemm64_kernel<64><<<(N + 31) / 32, 256, 0, stream>>>(x, W1, h1, N);
    att_kernel<32><<<nb4, 256, 0, stream>>>(h1, att_src1, att_dst1, asrc1, adst1, N);
    edge_softmax_kernel<<<nb4, 256, 0, stream>>>(asrc1, adst1, rowptr, csr, wnorm, N);
    agg_concat_kernel<<<nb4, 256, 0, stream>>>(h1, wnorm, rowptr, csr, b1, out1, N);

    // layer 2
    gemm64_kernel<128><<<(N + 15) / 16, 256, 0, stream>>>(out1, W2, h2, N);
    att_kernel<64><<<(N + 1) / 2, 256, 0, stream>>>(h2, att_src2, att_dst2, asrc2, adst2, N);
    edge_softmax_kernel<<<nb4, 256, 0, stream>>>(asrc2, adst2, rowptr, csr, wnorm, N);
    agg_mean_kernel<<<nb4, 256, 0, stream>>>(h2, wnorm, rowptr, csr, b2, out, N);
}

// Round 5
// 326.333 us; speedup vs baseline: 5.2979x; 1.0662x over previous
//
#include <hip/hip_runtime.h>
#include <hip/hip_fp16.h>

#define NEG_SLOPE 0.2f

__device__ __forceinline__ float lrelu(float a) { return a > 0.f ? a : NEG_SLOPE * a; }

struct half4 { __half2 a, b; };
__device__ __forceinline__ half4 pack_half4(float4 v) {
    half4 r; r.a = __floats2half2_rn(v.x, v.y); r.b = __floats2half2_rn(v.z, v.w); return r;
}
__device__ __forceinline__ void unpack8(uint4 u, float* f) {
    const __half2* hp = (const __half2*)&u;
#pragma unroll
    for (int i = 0; i < 4; i++) {
        float2 t = __half22float2(hp[i]);
        f[2 * i] = t.x; f[2 * i + 1] = t.y;
    }
}

// ---------------- CSR build ----------------

__global__ void hist_kernel(const int* __restrict__ dst, int E, int* __restrict__ deg) {
    int i = blockIdx.x * blockDim.x + threadIdx.x;
    int stride = gridDim.x * blockDim.x;
    for (int e = i; e < E; e += stride) atomicAdd(&deg[dst[e]], 1);
}

__global__ __launch_bounds__(1024) void scan_kernel(const int* __restrict__ deg,
                                                    int* __restrict__ rowptr, int N) {
    __shared__ int wsum[16];
    int t = threadIdx.x, lane = t & 63, w = t >> 6;
    int carry = 0;
    for (int base = 0; base < N; base += 1024) {
        int i = base + t;
        int v = (i < N) ? deg[i] + 1 : 0;
        int s = v;
#pragma unroll
        for (int off = 1; off < 64; off <<= 1) {
            int x = __shfl_up(s, off, 64);
            if (lane >= off) s += x;
        }
        if (lane == 63) wsum[w] = s;
        __syncthreads();
        if (w == 0) {
            int x = (lane < 16) ? wsum[lane] : 0;
#pragma unroll
            for (int off = 1; off < 16; off <<= 1) {
                int y = __shfl_up(x, off, 64);
                if (lane >= off) x += y;
            }
            if (lane < 16) wsum[lane] = x;
        }
        __syncthreads();
        int prefix = (w > 0) ? wsum[w - 1] : 0;
        int incl = s + prefix + carry;
        if (i < N) rowptr[i + 1] = incl;
        carry += wsum[15];
        __syncthreads();
    }
    if (t == 0) rowptr[0] = 0;
}

__global__ void scatter_kernel(const int* __restrict__ ei, int E, int Etot,
                               const int* __restrict__ rowptr, int* __restrict__ cursor,
                               int* __restrict__ csr) {
    int i = blockIdx.x * blockDim.x + threadIdx.x;
    int stride = gridDim.x * blockDim.x;
    for (int e = i; e < Etot; e += stride) {
        int s, d;
        if (e < E) { s = ei[e]; d = ei[E + e]; }
        else       { s = e - E; d = s; }
        int slot = atomicAdd(&cursor[d], 1);
        csr[rowptr[d] + slot] = s;
    }
}

// ---------------- GEMM: Yh[N,M] = fp16( X[N,64] @ W[64,M] ) ----------------

template <int M>
__global__ __launch_bounds__(256) void gemm64_kernel(const float* __restrict__ X,
                                                     const float* __restrict__ W,
                                                     __half* __restrict__ Yh, int N) {
    constexpr int CG = M / 4;
    constexpr int RB = (256 / CG) * 2;
    __shared__ float4 ws[64 * CG];
    __shared__ float  xs[RB][68];
    int t = threadIdx.x;
    for (int i = t; i < 64 * CG; i += 256) ws[i] = ((const float4*)W)[i];
    int r0 = blockIdx.x * RB;
    for (int i = t; i < RB * 16; i += 256) {
        int r = i >> 4, k4 = i & 15;
        int row = r0 + r;
        float4 v = (row < N) ? ((const float4*)X)[(size_t)row * 16 + k4]
                             : make_float4(0.f, 0.f, 0.f, 0.f);
        ((float4*)&xs[r][0])[k4] = v;
    }
    __syncthreads();
    int c = t % CG;
    int rl = (t / CG) * 2;
    float4 a0 = make_float4(0.f, 0.f, 0.f, 0.f);
    float4 a1 = make_float4(0.f, 0.f, 0.f, 0.f);
#pragma unroll
    for (int k = 0; k < 64; k++) {
        float4 w = ws[k * CG + c];
        float x0 = xs[rl][k];
        float x1 = xs[rl + 1][k];
        a0.x = fmaf(x0, w.x, a0.x); a0.y = fmaf(x0, w.y, a0.y);
        a0.z = fmaf(x0, w.z, a0.z); a0.w = fmaf(x0, w.w, a0.w);
        a1.x = fmaf(x1, w.x, a1.x); a1.y = fmaf(x1, w.y, a1.y);
        a1.z = fmaf(x1, w.z, a1.z); a1.w = fmaf(x1, w.w, a1.w);
    }
    int row0 = r0 + rl;
    if (row0 < N)     ((half4*)Yh)[(size_t)row0 * CG + c] = pack_half4(a0);
    if (row0 + 1 < N) ((half4*)Yh)[(size_t)(row0 + 1) * CG + c] = pack_half4(a1);
}

// ---------------- attention scores: a_src/a_dst [N,2] interleaved ----------------

template <int C>
__global__ __launch_bounds__(256) void att_kernel(const __half* __restrict__ h,
                                                  const float* __restrict__ att_src,
                                                  const float* __restrict__ att_dst,
                                                  float* __restrict__ a_src,
                                                  float* __restrict__ a_dst, int N) {
    constexpr int F = 2 * C;
    constexpr int NP = 256 / F;
    int node = blockIdx.x * NP + threadIdx.x / F;
    int f = threadIdx.x % F;
    int c = f % C;
    int hh = f / C;
    if (node >= N) return;
    float hv = __half2float(h[(size_t)node * F + f]);
    float vs = hv * att_src[f];
    float vd = hv * att_dst[f];
#pragma unroll
    for (int m = C / 2; m > 0; m >>= 1) {
        vs += __shfl_xor(vs, m, C);
        vd += __shfl_xor(vd, m, C);
    }
    if (c == 0) {
        a_src[node * 2 + hh] = vs;
        a_dst[node * 2 + hh] = vd;
    }
}

// ---------------- edge softmax: normalized weights in CSR order ----------------

__global__ __launch_bounds__(256) void edge_softmax_kernel(const float* __restrict__ a_src,
                                                           const float* __restrict__ a_dst,
                                                           const int* __restrict__ rowptr,
                                                           const int* __restrict__ csr,
                                                           float* __restrict__ wnorm,
                                                           int N) {
    int node = blockIdx.x * 4 + (threadIdx.x >> 6);
    int lane = threadIdx.x & 63;
    if (node >= N) return;
    int beg = rowptr[node], end = rowptr[node + 1];
    int deg = end - beg;
    float ad0 = a_dst[node * 2 + 0];
    float ad1 = a_dst[node * 2 + 1];
    if (deg <= 64) {
        float a0 = -1e30f, a1 = -1e30f;
        int e = beg + lane;
        if (lane < deg) {
            int s = csr[e];
            float2 as = ((const float2*)a_src)[s];
            a0 = lrelu(as.x + ad0);
            a1 = lrelu(as.y + ad1);
        }
        float m0 = a0, m1 = a1;
#pragma unroll
        for (int off = 32; off; off >>= 1) {
            m0 = fmaxf(m0, __shfl_xor(m0, off, 64));
            m1 = fmaxf(m1, __shfl_xor(m1, off, 64));
        }
        float w0 = (lane < deg) ? __expf(a0 - m0) : 0.f;
        float w1 = (lane < deg) ? __expf(a1 - m1) : 0.f;
        float d0 = w0, d1 = w1;
#pragma unroll
        for (int off = 32; off; off >>= 1) {
            d0 += __shfl_xor(d0, off, 64);
            d1 += __shfl_xor(d1, off, 64);
        }
        if (lane < deg)
            ((float2*)wnorm)[e] = make_float2(w0 / (d0 + 1e-16f), w1 / (d1 + 1e-16f));
    } else {
        float m0 = -1e30f, m1 = -1e30f;
        for (int i = lane; i < deg; i += 64) {
            int s = csr[beg + i];
            float2 as = ((const float2*)a_src)[s];
            m0 = fmaxf(m0, lrelu(as.x + ad0));
            m1 = fmaxf(m1, lrelu(as.y + ad1));
        }
#pragma unroll
        for (int off = 32; off; off >>= 1) {
            m0 = fmaxf(m0, __shfl_xor(m0, off, 64));
            m1 = fmaxf(m1, __shfl_xor(m1, off, 64));
        }
        float d0 = 0.f, d1 = 0.f;
        for (int i = lane; i < deg; i += 64) {
            int s = csr[beg + i];
            float2 as = ((const float2*)a_src)[s];
            d0 += __expf(lrelu(as.x + ad0) - m0);
            d1 += __expf(lrelu(as.y + ad1) - m1);
        }
#pragma unroll
        for (int off = 32; off; off >>= 1) {
            d0 += __shfl_xor(d0, off, 64);
            d1 += __shfl_xor(d1, off, 64);
        }
        float inv0 = 1.f / (d0 + 1e-16f), inv1 = 1.f / (d1 + 1e-16f);
        for (int i = lane; i < deg; i += 64) {
            int s = csr[beg + i];
            float2 as = ((const float2*)a_src)[s];
            ((float2*)wnorm)[beg + i] =
                make_float2(__expf(lrelu(as.x + ad0) - m0) * inv0,
                            __expf(lrelu(as.y + ad1) - m1) * inv1);
        }
    }
}

// -------- aggregation, layer 1 (concat; fp16 row = 64 halves = 128B) --------
// 8 edge-groups x 8 lanes; lane loads 16B (cols 8q..8q+7); head0 = q<4.

__global__ __launch_bounds__(256) void agg_concat_kernel(const __half* __restrict__ hg,
                                                         const float* __restrict__ wnorm,
                                                         const int* __restrict__ rowptr,
                                                         const int* __restrict__ csr,
                                                         const float* __restrict__ bias,
                                                         float* __restrict__ out, int N) {
    int node = blockIdx.x * 4 + (threadIdx.x >> 6);
    if (node >= N) return;
    int lane = threadIdx.x & 63;
    int g = lane >> 3, q = lane & 7;
    int beg = rowptr[node], end = rowptr[node + 1];
    float acc[8];
#pragma unroll
    for (int j = 0; j < 8; j++) acc[j] = 0.f;
    for (int e = beg + g; e < end; e += 8) {
        int s = csr[e];
        float2 wp = ((const float2*)wnorm)[e];
        float w = (q < 4) ? wp.x : wp.y;
        uint4 u = ((const uint4*)(hg + (size_t)s * 64))[q];
        float f[8];
        unpack8(u, f);
#pragma unroll
        for (int j = 0; j < 8; j++) acc[j] = fmaf(f[j], w, acc[j]);
    }
#pragma unroll
    for (int j = 0; j < 8; j++) {
        acc[j] += __shfl_xor(acc[j], 8, 64);
        acc[j] += __shfl_xor(acc[j], 16, 64);
        acc[j] += __shfl_xor(acc[j], 32, 64);
    }
    if (lane < 8) {
#pragma unroll
        for (int j4 = 0; j4 < 2; j4++) {
            float4 b = ((const float4*)bias)[2 * q + j4];
            float4 o;
            o.x = acc[4 * j4 + 0] + b.x;
            o.y = acc[4 * j4 + 1] + b.y;
            o.z = acc[4 * j4 + 2] + b.z;
            o.w = acc[4 * j4 + 3] + b.w;
            ((float4*)out)[(size_t)node * 16 + 2 * q + j4] = o;
        }
    }
}

// -------- aggregation, layer 2 (head-mean; fp16 row = 128 halves = 256B) --------
// 8 edge-groups x 8 lanes; lane loads 32B (cols 16q..16q+15); head0 = q<4.

__global__ __launch_bounds__(256) void agg_mean_kernel(const __half* __restrict__ hg,
                                                       const float* __restrict__ wnorm,
                                                       const int* __restrict__ rowptr,
                                                       const int* __restrict__ csr,
                                                       const float* __restrict__ bias,
                                                       float* __restrict__ out, int N) {
    int node = blockIdx.x * 4 + (threadIdx.x >> 6);
    if (node >= N) return;
    int lane = threadIdx.x & 63;
    int g = lane >> 3, q = lane & 7;
    int beg = rowptr[node], end = rowptr[node + 1];
    float acc[16];
#pragma unroll
    for (int j = 0; j < 16; j++) acc[j] = 0.f;
    for (int e = beg + g; e < end; e += 8) {
        int s = csr[e];
        float2 wp = ((const float2*)wnorm)[e];
        float w = (q < 4) ? wp.x : wp.y;
        const uint4* row = (const uint4*)(hg + (size_t)s * 128);
        uint4 u0 = row[2 * q];
        uint4 u1 = row[2 * q + 1];
        float f[16];
        unpack8(u0, f);
        unpack8(u1, f + 8);
#pragma unroll
        for (int j = 0; j < 16; j++) acc[j] = fmaf(f[j], w, acc[j]);
    }
#pragma unroll
    for (int j = 0; j < 16; j++) {
        acc[j] += __shfl_xor(acc[j], 8, 64);
        acc[j] += __shfl_xor(acc[j], 16, 64);
        acc[j] += __shfl_xor(acc[j], 32, 64);
    }
    float part[16];
#pragma unroll
    for (int j = 0; j < 16; j++) part[j] = __shfl_xor(acc[j], 4, 64);
    if (lane < 4) {  // g==0, q<4: cols 16q..16q+15
#pragma unroll
        for (int j4 = 0; j4 < 4; j4++) {
            float4 b = ((const float4*)bias)[4 * q + j4];
            float4 o;
            o.x = 0.5f * (acc[4 * j4 + 0] + part[4 * j4 + 0]) + b.x;
            o.y = 0.5f * (acc[4 * j4 + 1] + part[4 * j4 + 1]) + b.y;
            o.z = 0.5f * (acc[4 * j4 + 2] + part[4 * j4 + 2]) + b.z;
            o.w = 0.5f * (acc[4 * j4 + 3] + part[4 * j4 + 3]) + b.w;
            ((float4*)out)[(size_t)node * 16 + 4 * q + j4] = o;
        }
    }
}

// ---------------- launch ----------------

extern "C" void kernel_launch(void* const* d_in, const int* in_sizes, int n_in,
                              void* d_out, int out_size, void* d_ws, size_t ws_size,
                              hipStream_t stream) {
    const float* x        = (const float*)d_in[0];
    const int*   ei       = (const int*)d_in[1];
    const float* W1       = (const float*)d_in[2];
    const float* att_src1 = (const float*)d_in[3];
    const float* att_dst1 = (const float*)d_in[4];
    const float* b1       = (const float*)d_in[5];
    const float* W2       = (const float*)d_in[6];
    const float* att_src2 = (const float*)d_in[7];
    const float* att_dst2 = (const float*)d_in[8];
    const float* b2       = (const float*)d_in[9];
    float* out = (float*)d_out;

    const int N = in_sizes[0] / 64;
    const int E = in_sizes[1] / 2;
    const int Etot = E + N;

    char* base = (char*)d_ws;
    size_t off = 0;
    auto alloc = [&](size_t bytes) -> char* {
        char* p = base + off;
        off = (off + bytes + 255) & ~(size_t)255;
        return p;
    };
    int*    deg    = (int*)alloc((size_t)N * 4);          // reused as cursor
    int*    rowptr = (int*)alloc((size_t)(N + 1) * 4);
    int*    csr    = (int*)alloc((size_t)Etot * 4);
    __half* h1g    = (__half*)alloc((size_t)N * 64 * 2);
    float*  asrc1  = (float*)alloc((size_t)N * 2 * 4);
    float*  adst1  = (float*)alloc((size_t)N * 2 * 4);
    float*  out1   = (float*)alloc((size_t)N * 64 * 4);
    __half* h2g    = (__half*)alloc((size_t)N * 128 * 2);
    float*  asrc2  = (float*)alloc((size_t)N * 2 * 4);
    float*  adst2  = (float*)alloc((size_t)N * 2 * 4);
    float*  wnorm  = (float*)alloc((size_t)Etot * 2 * 4); // reused by both layers
    (void)ws_size; (void)n_in; (void)out_size;

    // CSR build (shared by both layers)
    hipMemsetAsync(deg, 0, (size_t)N * 4, stream);
    hist_kernel<<<(E + 255) / 256, 256, 0, stream>>>(ei + E, E, deg);
    scan_kernel<<<1, 1024, 0, stream>>>(deg, rowptr, N);
    hipMemsetAsync(deg, 0, (size_t)N * 4, stream);
    scatter_kernel<<<(Etot + 255) / 256, 256, 0, stream>>>(ei, E, Etot, rowptr, deg, csr);

    int nb4 = (N + 3) / 4;

    // layer 1
    gemm64_kernel<64><<<(N + 31) / 32, 256, 0, stream>>>(x, W1, h1g, N);
    att_kernel<32><<<nb4, 256, 0, stream>>>(h1g, att_src1, att_dst1, asrc1, adst1, N);
    edge_softmax_kernel<<<nb4, 256, 0, stream>>>(asrc1, adst1, rowptr, csr, wnorm, N);
    agg_concat_kernel<<<nb4, 256, 0, stream>>>(h1g, wnorm, rowptr, csr, b1, out1, N);

    // layer 2
    gemm64_kernel<128><<<(N + 15) / 16, 256, 0, stream>>>(out1, W2, h2g, N);
    att_kernel<64><<<(N + 1) / 2, 256, 0, stream>>>(h2g, att_src2, att_dst2, asrc2, adst2, N);
    edge_softmax_kernel<<<nb4, 256, 0, stream>>>(asrc2, adst2, rowptr, csr, wnorm, N);
    agg_mean_kernel<<<nb4, 256, 0, stream>>>(h2g, wnorm, rowptr, csr, b2, out, N);
}

// Round 6
// 258.902 us; speedup vs baseline: 6.6778x; 1.2605x over previous
//
#include <hip/hip_runtime.h>
#include <hip/hip_fp16.h>

#define NEG_SLOPE 0.2f

__device__ __forceinline__ float lrelu(float a) { return a > 0.f ? a : NEG_SLOPE * a; }

struct half4 { __half2 a, b; };
__device__ __forceinline__ half4 pack_half4(float4 v) {
    half4 r; r.a = __floats2half2_rn(v.x, v.y); r.b = __floats2half2_rn(v.z, v.w); return r;
}
__device__ __forceinline__ void unpack8(uint4 u, float* f) {
    const __half2* hp = (const __half2*)&u;
#pragma unroll
    for (int i = 0; i < 4; i++) {
        float2 t = __half22float2(hp[i]);
        f[2 * i] = t.x; f[2 * i + 1] = t.y;
    }
}

// ---------------- CSR build ----------------

__global__ void hist_kernel(const int* __restrict__ dst, int E, int* __restrict__ deg) {
    int i = blockIdx.x * blockDim.x + threadIdx.x;
    int stride = gridDim.x * blockDim.x;
    for (int e = i; e < E; e += stride) atomicAdd(&deg[dst[e]], 1);
}

__global__ __launch_bounds__(1024) void scan_kernel(const int* __restrict__ deg,
                                                    int* __restrict__ rowptr, int N) {
    __shared__ int wsum[16];
    int t = threadIdx.x, lane = t & 63, w = t >> 6;
    int carry = 0;
    for (int base = 0; base < N; base += 1024) {
        int i = base + t;
        int v = (i < N) ? deg[i] + 1 : 0;
        int s = v;
#pragma unroll
        for (int off = 1; off < 64; off <<= 1) {
            int x = __shfl_up(s, off, 64);
            if (lane >= off) s += x;
        }
        if (lane == 63) wsum[w] = s;
        __syncthreads();
        if (w == 0) {
            int x = (lane < 16) ? wsum[lane] : 0;
#pragma unroll
            for (int off = 1; off < 16; off <<= 1) {
                int y = __shfl_up(x, off, 64);
                if (lane >= off) x += y;
            }
            if (lane < 16) wsum[lane] = x;
        }
        __syncthreads();
        int prefix = (w > 0) ? wsum[w - 1] : 0;
        int incl = s + prefix + carry;
        if (i < N) rowptr[i + 1] = incl;
        carry += wsum[15];
        __syncthreads();
    }
    if (t == 0) rowptr[0] = 0;
}

// bucket = 256 consecutive dst nodes. bcur[bk] starts at rowptr[bk*256].
__global__ void initb_kernel(const int* __restrict__ rowptr, int* __restrict__ bcur,
                             int NBK, int N) {
    int t = threadIdx.x;
    for (int b = t; b < NBK; b += 256) {
        int n0 = b << 8;
        bcur[b] = rowptr[n0 < N ? n0 : N];
    }
}

// Pass A: tile 4096 edges/block; LDS histogram over buckets; reserve dense per-
// (block,bucket) ranges via one global atomic each; write (src,dst) runs.
__global__ __launch_bounds__(256) void bucketA_kernel(const int* __restrict__ ei, int E,
                                                      int Etot, int* __restrict__ bcur,
                                                      uint2* __restrict__ btmp) {
    __shared__ int lh[256];
    __shared__ int lbase[256];
    int t = threadIdx.x;
    int b0 = blockIdx.x * 4096;
    lh[t] = 0;
    __syncthreads();
    int s[16], d[16], bk[16];
#pragma unroll
    for (int i = 0; i < 16; i++) {
        int e = b0 + i * 256 + t;
        if (e < Etot) {
            int ss, dd;
            if (e < E) { ss = ei[e]; dd = ei[E + e]; }
            else       { ss = e - E; dd = ss; }
            s[i] = ss; d[i] = dd; bk[i] = dd >> 8;
            atomicAdd(&lh[bk[i]], 1);
        } else bk[i] = -1;
    }
    __syncthreads();
    if (lh[t] > 0) lbase[t] = atomicAdd(&bcur[t], lh[t]);
    __syncthreads();
    lh[t] = 0;
    __syncthreads();
#pragma unroll
    for (int i = 0; i < 16; i++) {
        if (bk[i] >= 0) {
            int pos = lbase[bk[i]] + atomicAdd(&lh[bk[i]], 1);
            btmp[pos] = make_uint2((unsigned)s[i], (unsigned)d[i]);
        }
    }
}

// Pass B: one block per bucket; per-node cursors + rowptr slice in LDS;
// csr writes confined to the bucket's contiguous output region.
__global__ __launch_bounds__(256) void bucketB_kernel(const uint2* __restrict__ btmp,
                                                      const int* __restrict__ rowptr,
                                                      int N, int* __restrict__ csr) {
    __shared__ int lcur[256];
    __shared__ int lrow[257];
    int bkt = blockIdx.x;
    int n0 = bkt << 8;
    int n1 = n0 + 256; if (n1 > N) n1 = N;
    int nn = n1 - n0;
    int t = threadIdx.x;
    lcur[t] = 0;
    if (t < nn) lrow[t] = rowptr[n0 + t];
    if (t == 0) lrow[nn] = rowptr[n1];
    __syncthreads();
    int ebeg = lrow[0], eend = lrow[nn];
    for (int e = ebeg + t; e < eend; e += 256) {
        uint2 sd = btmp[e];
        int dl = (int)sd.y - n0;
        int slot = atomicAdd(&lcur[dl], 1);
        csr[lrow[dl] + slot] = (int)sd.x;
    }
}

// ---------------- GEMM: Yh[N,M] = fp16( X[N,64] @ W[64,M] ) ----------------

template <int M>
__global__ __launch_bounds__(256) void gemm64_kernel(const float* __restrict__ X,
                                                     const float* __restrict__ W,
                                                     __half* __restrict__ Yh, int N) {
    constexpr int CG = M / 4;
    constexpr int RB = (256 / CG) * 2;
    __shared__ float4 ws[64 * CG];
    __shared__ float  xs[RB][68];
    int t = threadIdx.x;
    for (int i = t; i < 64 * CG; i += 256) ws[i] = ((const float4*)W)[i];
    int r0 = blockIdx.x * RB;
    for (int i = t; i < RB * 16; i += 256) {
        int r = i >> 4, k4 = i & 15;
        int row = r0 + r;
        float4 v = (row < N) ? ((const float4*)X)[(size_t)row * 16 + k4]
                             : make_float4(0.f, 0.f, 0.f, 0.f);
        ((float4*)&xs[r][0])[k4] = v;
    }
    __syncthreads();
    int c = t % CG;
    int rl = (t / CG) * 2;
    float4 a0 = make_float4(0.f, 0.f, 0.f, 0.f);
    float4 a1 = make_float4(0.f, 0.f, 0.f, 0.f);
#pragma unroll 8
    for (int k = 0; k < 64; k++) {
        float4 w = ws[k * CG + c];
        float x0 = xs[rl][k];
        float x1 = xs[rl + 1][k];
        a0.x = fmaf(x0, w.x, a0.x); a0.y = fmaf(x0, w.y, a0.y);
        a0.z = fmaf(x0, w.z, a0.z); a0.w = fmaf(x0, w.w, a0.w);
        a1.x = fmaf(x1, w.x, a1.x); a1.y = fmaf(x1, w.y, a1.y);
        a1.z = fmaf(x1, w.z, a1.z); a1.w = fmaf(x1, w.w, a1.w);
    }
    int row0 = r0 + rl;
    if (row0 < N)     ((half4*)Yh)[(size_t)row0 * CG + c] = pack_half4(a0);
    if (row0 + 1 < N) ((half4*)Yh)[(size_t)(row0 + 1) * CG + c] = pack_half4(a1);
}

// ---------------- attention scores: a_src/a_dst [N,2] interleaved ----------------

template <int C>
__global__ __launch_bounds__(256) void att_kernel(const __half* __restrict__ h,
                                                  const float* __restrict__ att_src,
                                                  const float* __restrict__ att_dst,
                                                  float* __restrict__ a_src,
                                                  float* __restrict__ a_dst, int N) {
    constexpr int F = 2 * C;
    constexpr int NP = 256 / F;
    int node = blockIdx.x * NP + threadIdx.x / F;
    int f = threadIdx.x % F;
    int c = f % C;
    int hh = f / C;
    if (node >= N) return;
    float hv = __half2float(h[(size_t)node * F + f]);
    float vs = hv * att_src[f];
    float vd = hv * att_dst[f];
#pragma unroll
    for (int m = C / 2; m > 0; m >>= 1) {
        vs += __shfl_xor(vs, m, C);
        vd += __shfl_xor(vd, m, C);
    }
    if (c == 0) {
        a_src[node * 2 + hh] = vs;
        a_dst[node * 2 + hh] = vd;
    }
}

// ---------------- edge softmax: normalized weights in CSR order ----------------

__global__ __launch_bounds__(256) void edge_softmax_kernel(const float* __restrict__ a_src,
                                                           const float* __restrict__ a_dst,
                                                           const int* __restrict__ rowptr,
                                                           const int* __restrict__ csr,
                                                           float* __restrict__ wnorm,
                                                           int N) {
    int node = blockIdx.x * 4 + (threadIdx.x >> 6);
    int lane = threadIdx.x & 63;
    if (node >= N) return;
    int beg = rowptr[node], end = rowptr[node + 1];
    int deg = end - beg;
    float ad0 = a_dst[node * 2 + 0];
    float ad1 = a_dst[node * 2 + 1];
    if (deg <= 64) {
        float a0 = -1e30f, a1 = -1e30f;
        int e = beg + lane;
        if (lane < deg) {
            int s = csr[e];
            float2 as = ((const float2*)a_src)[s];
            a0 = lrelu(as.x + ad0);
            a1 = lrelu(as.y + ad1);
        }
        float m0 = a0, m1 = a1;
#pragma unroll
        for (int off = 32; off; off >>= 1) {
            m0 = fmaxf(m0, __shfl_xor(m0, off, 64));
            m1 = fmaxf(m1, __shfl_xor(m1, off, 64));
        }
        float w0 = (lane < deg) ? __expf(a0 - m0) : 0.f;
        float w1 = (lane < deg) ? __expf(a1 - m1) : 0.f;
        float d0 = w0, d1 = w1;
#pragma unroll
        for (int off = 32; off; off >>= 1) {
            d0 += __shfl_xor(d0, off, 64);
            d1 += __shfl_xor(d1, off, 64);
        }
        if (lane < deg)
            ((float2*)wnorm)[e] = make_float2(w0 / (d0 + 1e-16f), w1 / (d1 + 1e-16f));
    } else {
        float m0 = -1e30f, m1 = -1e30f;
        for (int i = lane; i < deg; i += 64) {
            int s = csr[beg + i];
            float2 as = ((const float2*)a_src)[s];
            m0 = fmaxf(m0, lrelu(as.x + ad0));
            m1 = fmaxf(m1, lrelu(as.y + ad1));
        }
#pragma unroll
        for (int off = 32; off; off >>= 1) {
            m0 = fmaxf(m0, __shfl_xor(m0, off, 64));
            m1 = fmaxf(m1, __shfl_xor(m1, off, 64));
        }
        float d0 = 0.f, d1 = 0.f;
        for (int i = lane; i < deg; i += 64) {
            int s = csr[beg + i];
            float2 as = ((const float2*)a_src)[s];
            d0 += __expf(lrelu(as.x + ad0) - m0);
            d1 += __expf(lrelu(as.y + ad1) - m1);
        }
#pragma unroll
        for (int off = 32; off; off >>= 1) {
            d0 += __shfl_xor(d0, off, 64);
            d1 += __shfl_xor(d1, off, 64);
        }
        float inv0 = 1.f / (d0 + 1e-16f), inv1 = 1.f / (d1 + 1e-16f);
        for (int i = lane; i < deg; i += 64) {
            int s = csr[beg + i];
            float2 as = ((const float2*)a_src)[s];
            ((float2*)wnorm)[beg + i] =
                make_float2(__expf(lrelu(as.x + ad0) - m0) * inv0,
                            __expf(lrelu(as.y + ad1) - m1) * inv1);
        }
    }
}

// -------- aggregation, layer 1 (concat; fp16 row = 64 halves = 128B) --------

__global__ __launch_bounds__(256) void agg_concat_kernel(const __half* __restrict__ hg,
                                                         const float* __restrict__ wnorm,
                                                         const int* __restrict__ rowptr,
                                                         const int* __restrict__ csr,
                                                         const float* __restrict__ bias,
                                                         float* __restrict__ out, int N) {
    int node = blockIdx.x * 4 + (threadIdx.x >> 6);
    if (node >= N) return;
    int lane = threadIdx.x & 63;
    int g = lane >> 3, q = lane & 7;
    int beg = rowptr[node], end = rowptr[node + 1];
    float acc[8];
#pragma unroll
    for (int j = 0; j < 8; j++) acc[j] = 0.f;
    for (int e = beg + g; e < end; e += 8) {
        int s = csr[e];
        float2 wp = ((const float2*)wnorm)[e];
        float w = (q < 4) ? wp.x : wp.y;
        uint4 u = ((const uint4*)(hg + (size_t)s * 64))[q];
        float f[8];
        unpack8(u, f);
#pragma unroll
        for (int j = 0; j < 8; j++) acc[j] = fmaf(f[j], w, acc[j]);
    }
#pragma unroll
    for (int j = 0; j < 8; j++) {
        acc[j] += __shfl_xor(acc[j], 8, 64);
        acc[j] += __shfl_xor(acc[j], 16, 64);
        acc[j] += __shfl_xor(acc[j], 32, 64);
    }
    if (lane < 8) {
#pragma unroll
        for (int j4 = 0; j4 < 2; j4++) {
            float4 b = ((const float4*)bias)[2 * q + j4];
            float4 o;
            o.x = acc[4 * j4 + 0] + b.x;
            o.y = acc[4 * j4 + 1] + b.y;
            o.z = acc[4 * j4 + 2] + b.z;
            o.w = acc[4 * j4 + 3] + b.w;
            ((float4*)out)[(size_t)node * 16 + 2 * q + j4] = o;
        }
    }
}

// -------- aggregation, layer 2 (head-mean; fp16 row = 128 halves = 256B) --------

__global__ __launch_bounds__(256) void agg_mean_kernel(const __half* __restrict__ hg,
                                                       const float* __restrict__ wnorm,
                                                       const int* __restrict__ rowptr,
                                                       const int* __restrict__ csr,
                                                       const float* __restrict__ bias,
                                                       float* __restrict__ out, int N) {
    int node = blockIdx.x * 4 + (threadIdx.x >> 6);
    if (node >= N) return;
    int lane = threadIdx.x & 63;
    int g = lane >> 3, q = lane & 7;
    int beg = rowptr[node], end = rowptr[node + 1];
    float acc[16];
#pragma unroll
    for (int j = 0; j < 16; j++) acc[j] = 0.f;
    for (int e = beg + g; e < end; e += 8) {
        int s = csr[e];
        float2 wp = ((const float2*)wnorm)[e];
        float w = (q < 4) ? wp.x : wp.y;
        const uint4* row = (const uint4*)(hg + (size_t)s * 128);
        uint4 u0 = row[2 * q];
        uint4 u1 = row[2 * q + 1];
        float f[16];
        unpack8(u0, f);
        unpack8(u1, f + 8);
#pragma unroll
        for (int j = 0; j < 16; j++) acc[j] = fmaf(f[j], w, acc[j]);
    }
#pragma unroll
    for (int j = 0; j < 16; j++) {
        acc[j] += __shfl_xor(acc[j], 8, 64);
        acc[j] += __shfl_xor(acc[j], 16, 64);
        acc[j] += __shfl_xor(acc[j], 32, 64);
    }
    float part[16];
#pragma unroll
    for (int j = 0; j < 16; j++) part[j] = __shfl_xor(acc[j], 4, 64);
    if (lane < 4) {
#pragma unroll
        for (int j4 = 0; j4 < 4; j4++) {
            float4 b = ((const float4*)bias)[4 * q + j4];
            float4 o;
            o.x = 0.5f * (acc[4 * j4 + 0] + part[4 * j4 + 0]) + b.x;
            o.y = 0.5f * (acc[4 * j4 + 1] + part[4 * j4 + 1]) + b.y;
            o.z = 0.5f * (acc[4 * j4 + 2] + part[4 * j4 + 2]) + b.z;
            o.w = 0.5f * (acc[4 * j4 + 3] + part[4 * j4 + 3]) + b.w;
            ((float4*)out)[(size_t)node * 16 + 4 * q + j4] = o;
        }
    }
}

// ---------------- launch ----------------

extern "C" void kernel_launch(void* const* d_in, const int* in_sizes, int n_in,
                              void* d_out, int out_size, void* d_ws, size_t ws_size,
                              hipStream_t stream) {
    const float* x        = (const float*)d_in[0];
    const int*   ei       = (const int*)d_in[1];
    const float* W1       = (const float*)d_in[2];
    const float* att_src1 = (const float*)d_in[3];
    const float* att_dst1 = (const float*)d_in[4];
    const float* b1       = (const float*)d_in[5];
    const float* W2       = (const float*)d_in[6];
    const float* att_src2 = (const float*)d_in[7];
    const float* att_dst2 = (const float*)d_in[8];
    const float* b2       = (const float*)d_in[9];
    float* out = (float*)d_out;

    const int N = in_sizes[0] / 64;
    const int E = in_sizes[1] / 2;
    const int Etot = E + N;
    const int NBK = (N + 255) >> 8;

    char* base = (char*)d_ws;
    size_t off = 0;
    auto alloc = [&](size_t bytes) -> char* {
        char* p = base + off;
        off = (off + bytes + 255) & ~(size_t)255;
        return p;
    };
    int*    deg    = (int*)alloc((size_t)N * 4);
    int*    rowptr = (int*)alloc((size_t)(N + 1) * 4);
    int*    csr    = (int*)alloc((size_t)Etot * 4);
    int*    bcur   = (int*)alloc((size_t)NBK * 4);
    uint2*  btmp   = (uint2*)alloc((size_t)Etot * 8);
    __half* h1g    = (__half*)alloc((size_t)N * 64 * 2);
    float*  asrc1  = (float*)alloc((size_t)N * 2 * 4);
    float*  adst1  = (float*)alloc((size_t)N * 2 * 4);
    float*  out1   = (float*)alloc((size_t)N * 64 * 4);
    __half* h2g    = (__half*)alloc((size_t)N * 128 * 2);
    float*  asrc2  = (float*)alloc((size_t)N * 2 * 4);
    float*  adst2  = (float*)alloc((size_t)N * 2 * 4);
    float*  wnorm  = (float*)alloc((size_t)Etot * 2 * 4);
    (void)ws_size; (void)n_in; (void)out_size;

    // CSR build (bucketed counting sort; shared by both layers)
    hipMemsetAsync(deg, 0, (size_t)N * 4, stream);
    hist_kernel<<<(E + 255) / 256, 256, 0, stream>>>(ei + E, E, deg);
    scan_kernel<<<1, 1024, 0, stream>>>(deg, rowptr, N);
    initb_kernel<<<1, 256, 0, stream>>>(rowptr, bcur, NBK, N);
    bucketA_kernel<<<(Etot + 4095) / 4096, 256, 0, stream>>>(ei, E, Etot, bcur, btmp);
    bucketB_kernel<<<NBK, 256, 0, stream>>>(btmp, rowptr, N, csr);

    int nb4 = (N + 3) / 4;

    // layer 1
    gemm64_kernel<64><<<(N + 31) / 32, 256, 0, stream>>>(x, W1, h1g, N);
    att_kernel<32><<<nb4, 256, 0, stream>>>(h1g, att_src1, att_dst1, asrc1, adst1, N);
    edge_softmax_kernel<<<nb4, 256, 0, stream>>>(asrc1, adst1, rowptr, csr, wnorm, N);
    agg_concat_kernel<<<nb4, 256, 0, stream>>>(h1g, wnorm, rowptr, csr, b1, out1, N);

    // layer 2
    gemm64_kernel<128><<<(N + 15) / 16, 256, 0, stream>>>(out1, W2, h2g, N);
    att_kernel<64><<<(N + 1) / 2, 256, 0, stream>>>(h2g, att_src2, att_dst2, asrc2, adst2, N);
    edge_softmax_kernel<<<nb4, 256, 0, stream>>>(asrc2, adst2, rowptr, csr, wnorm, N);
    agg_mean_kernel<<<nb4, 256, 0, stream>>>(h2g, wnorm, rowptr, csr, b2, out, N);
}

// Round 7
// 204.687 us; speedup vs baseline: 8.4465x; 1.2649x over previous
//
#include <hip/hip_runtime.h>
#include <hip/hip_fp16.h>

#define NEG_SLOPE 0.2f

__device__ __forceinline__ float lrelu(float a) { return a > 0.f ? a : NEG_SLOPE * a; }

struct half4 { __half2 a, b; };
__device__ __forceinline__ half4 pack_half4(float4 v) {
    half4 r; r.a = __floats2half2_rn(v.x, v.y); r.b = __floats2half2_rn(v.z, v.w); return r;
}
__device__ __forceinline__ void unpack8(uint4 u, float* f) {
    const __half2* hp = (const __half2*)&u;
#pragma unroll
    for (int i = 0; i < 4; i++) {
        float2 t = __half22float2(hp[i]);
        f[2 * i] = t.x; f[2 * i + 1] = t.y;
    }
}

// ---------------- CSR build ----------------

__global__ void hist_kernel(const int* __restrict__ dst, int E, int* __restrict__ deg) {
    int i = blockIdx.x * blockDim.x + threadIdx.x;
    int stride = gridDim.x * blockDim.x;
    for (int e = i; e < E; e += stride) atomicAdd(&deg[dst[e]], 1);
}

// hierarchical exclusive scan of (deg[i]+1), chunk = 512 elements per 256-thread block
__global__ __launch_bounds__(256) void scan_local_kernel(const int* __restrict__ deg,
                                                         int* __restrict__ rowptr,
                                                         int* __restrict__ csum, int N) {
    __shared__ int wsum[4];
    int blk = blockIdx.x, t = threadIdx.x;
    int base = blk * 512;
    int i0 = base + 2 * t;
    int v0 = (i0 < N) ? deg[i0] + 1 : 0;
    int v1 = (i0 + 1 < N) ? deg[i0 + 1] + 1 : 0;
    int p = v0 + v1;
    int lane = t & 63, w = t >> 6;
    int s = p;
#pragma unroll
    for (int off = 1; off < 64; off <<= 1) {
        int x = __shfl_up(s, off, 64);
        if (lane >= off) s += x;
    }
    if (lane == 63) wsum[w] = s;
    __syncthreads();
    int woff = 0;
    if (w > 0) woff += wsum[0];
    if (w > 1) woff += wsum[1];
    if (w > 2) woff += wsum[2];
    int epre = woff + s - p;  // exclusive prefix for this pair
    if (i0 < N)     rowptr[i0 + 1] = epre + v0;
    if (i0 + 1 < N) rowptr[i0 + 2] = epre + v0 + v1;
    if (t == 255) csum[blk] = woff + s;
}

__global__ __launch_bounds__(256) void scan_sums_kernel(int* __restrict__ csum, int NCH) {
    __shared__ int wsum[4];
    int t = threadIdx.x, lane = t & 63, w = t >> 6;
    int v = (t < NCH) ? csum[t] : 0;
    int s = v;
#pragma unroll
    for (int off = 1; off < 64; off <<= 1) {
        int x = __shfl_up(s, off, 64);
        if (lane >= off) s += x;
    }
    if (lane == 63) wsum[w] = s;
    __syncthreads();
    int woff = 0;
    if (w > 0) woff += wsum[0];
    if (w > 1) woff += wsum[1];
    if (w > 2) woff += wsum[2];
    if (t < NCH) csum[t] = woff + s - v;  // exclusive
}

__global__ __launch_bounds__(256) void scan_add_kernel(const int* __restrict__ csum,
                                                       int* __restrict__ rowptr, int N) {
    int blk = blockIdx.x, t = threadIdx.x;
    int off = csum[blk];
    int i0 = blk * 512 + 2 * t;
    if (blk == 0 && t == 0) rowptr[0] = 0;
    if (i0 < N)     rowptr[i0 + 1] += off;
    if (i0 + 1 < N) rowptr[i0 + 2] += off;
}

// bucket = 256 consecutive dst nodes. bcur[bk] starts at rowptr[bk*256].
__global__ void initb_kernel(const int* __restrict__ rowptr, int* __restrict__ bcur,
                             int NBK, int N) {
    int t = threadIdx.x;
    for (int b = t; b < NBK; b += 256) {
        int n0 = b << 8;
        bcur[b] = rowptr[n0 < N ? n0 : N];
    }
}

// Pass A: tile 4096 edges/block; LDS histogram over buckets; reserve dense per-
// (block,bucket) ranges via one global atomic each; write (src,dst) runs.
__global__ __launch_bounds__(256) void bucketA_kernel(const int* __restrict__ ei, int E,
                                                      int Etot, int* __restrict__ bcur,
                                                      uint2* __restrict__ btmp) {
    __shared__ int lh[256];
    __shared__ int lbase[256];
    int t = threadIdx.x;
    int b0 = blockIdx.x * 4096;
    lh[t] = 0;
    __syncthreads();
    int s[16], d[16], bk[16];
#pragma unroll
    for (int i = 0; i < 16; i++) {
        int e = b0 + i * 256 + t;
        if (e < Etot) {
            int ss, dd;
            if (e < E) { ss = ei[e]; dd = ei[E + e]; }
            else       { ss = e - E; dd = ss; }
            s[i] = ss; d[i] = dd; bk[i] = dd >> 8;
            atomicAdd(&lh[bk[i]], 1);
        } else bk[i] = -1;
    }
    __syncthreads();
    if (lh[t] > 0) lbase[t] = atomicAdd(&bcur[t], lh[t]);
    __syncthreads();
    lh[t] = 0;
    __syncthreads();
#pragma unroll
    for (int i = 0; i < 16; i++) {
        if (bk[i] >= 0) {
            int pos = lbase[bk[i]] + atomicAdd(&lh[bk[i]], 1);
            btmp[pos] = make_uint2((unsigned)s[i], (unsigned)d[i]);
        }
    }
}

// Pass B: one block per bucket; per-node cursors + rowptr slice in LDS.
__global__ __launch_bounds__(256) void bucketB_kernel(const uint2* __restrict__ btmp,
                                                      const int* __restrict__ rowptr,
                                                      int N, int* __restrict__ csr) {
    __shared__ int lcur[256];
    __shared__ int lrow[257];
    int bkt = blockIdx.x;
    int n0 = bkt << 8;
    int n1 = n0 + 256; if (n1 > N) n1 = N;
    int nn = n1 - n0;
    int t = threadIdx.x;
    lcur[t] = 0;
    if (t < nn) lrow[t] = rowptr[n0 + t];
    if (t == 0) lrow[nn] = rowptr[n1];
    __syncthreads();
    int ebeg = lrow[0], eend = lrow[nn];
    for (int e = ebeg + t; e < eend; e += 256) {
        uint2 sd = btmp[e];
        int dl = (int)sd.y - n0;
        int slot = atomicAdd(&lcur[dl], 1);
        csr[lrow[dl] + slot] = (int)sd.x;
    }
}

// ------- GEMM + fused att scores: Yh = fp16(X @ W), a_src/a_dst [N,2] -------

template <int M>
__global__ __launch_bounds__(256) void gemm64_kernel(const float* __restrict__ X,
                                                     const float* __restrict__ W,
                                                     __half* __restrict__ Yh,
                                                     const float* __restrict__ att_s,
                                                     const float* __restrict__ att_d,
                                                     float* __restrict__ a_src,
                                                     float* __restrict__ a_dst, int N) {
    constexpr int CG = M / 4;
    constexpr int RB = (256 / CG) * 2;
    constexpr int HL = CG / 2;  // lanes per head group: 8 (M=64) or 16 (M=128)
    __shared__ float4 ws[64 * CG];
    __shared__ float  xs[RB][68];
    int t = threadIdx.x;
    for (int i = t; i < 64 * CG; i += 256) ws[i] = ((const float4*)W)[i];
    int r0 = blockIdx.x * RB;
    for (int i = t; i < RB * 16; i += 256) {
        int r = i >> 4, k4 = i & 15;
        int row = r0 + r;
        float4 v = (row < N) ? ((const float4*)X)[(size_t)row * 16 + k4]
                             : make_float4(0.f, 0.f, 0.f, 0.f);
        ((float4*)&xs[r][0])[k4] = v;
    }
    __syncthreads();
    int c = t % CG;
    int rl = (t / CG) * 2;
    float4 a0 = make_float4(0.f, 0.f, 0.f, 0.f);
    float4 a1 = make_float4(0.f, 0.f, 0.f, 0.f);
#pragma unroll 8
    for (int k = 0; k < 64; k++) {
        float4 w = ws[k * CG + c];
        float x0 = xs[rl][k];
        float x1 = xs[rl + 1][k];
        a0.x = fmaf(x0, w.x, a0.x); a0.y = fmaf(x0, w.y, a0.y);
        a0.z = fmaf(x0, w.z, a0.z); a0.w = fmaf(x0, w.w, a0.w);
        a1.x = fmaf(x1, w.x, a1.x); a1.y = fmaf(x1, w.y, a1.y);
        a1.z = fmaf(x1, w.z, a1.z); a1.w = fmaf(x1, w.w, a1.w);
    }
    int row0 = r0 + rl;
    if (row0 < N)     ((half4*)Yh)[(size_t)row0 * CG + c] = pack_half4(a0);
    if (row0 + 1 < N) ((half4*)Yh)[(size_t)(row0 + 1) * CG + c] = pack_half4(a1);

    // fused attention scores (per-head dot + 8/16-lane reduce)
    float4 s4 = ((const float4*)att_s)[c];
    float4 d4 = ((const float4*)att_d)[c];
    float vs0 = a0.x * s4.x + a0.y * s4.y + a0.z * s4.z + a0.w * s4.w;
    float vd0 = a0.x * d4.x + a0.y * d4.y + a0.z * d4.z + a0.w * d4.w;
    float vs1 = a1.x * s4.x + a1.y * s4.y + a1.z * s4.z + a1.w * s4.w;
    float vd1 = a1.x * d4.x + a1.y * d4.y + a1.z * d4.z + a1.w * d4.w;
#pragma unroll
    for (int off = 1; off < HL; off <<= 1) {
        vs0 += __shfl_xor(vs0, off, 64);
        vd0 += __shfl_xor(vd0, off, 64);
        vs1 += __shfl_xor(vs1, off, 64);
        vd1 += __shfl_xor(vd1, off, 64);
    }
    if ((c & (HL - 1)) == 0) {
        int hh = c / HL;
        if (row0 < N)     { a_src[row0 * 2 + hh] = vs0; a_dst[row0 * 2 + hh] = vd0; }
        if (row0 + 1 < N) { a_src[(row0 + 1) * 2 + hh] = vs1; a_dst[(row0 + 1) * 2 + hh] = vd1; }
    }
}

// ---------------- edge softmax: normalized weights in CSR order ----------------

__global__ __launch_bounds__(256) void edge_softmax_kernel(const float* __restrict__ a_src,
                                                           const float* __restrict__ a_dst,
                                                           const int* __restrict__ rowptr,
                                                           const int* __restrict__ csr,
                                                           float* __restrict__ wnorm,
                                                           int N) {
    int node = blockIdx.x * 4 + (threadIdx.x >> 6);
    int lane = threadIdx.x & 63;
    if (node >= N) return;
    int beg = rowptr[node], end = rowptr[node + 1];
    int deg = end - beg;
    float ad0 = a_dst[node * 2 + 0];
    float ad1 = a_dst[node * 2 + 1];
    if (deg <= 64) {
        float a0 = -1e30f, a1 = -1e30f;
        int e = beg + lane;
        if (lane < deg) {
            int s = csr[e];
            float2 as = ((const float2*)a_src)[s];
            a0 = lrelu(as.x + ad0);
            a1 = lrelu(as.y + ad1);
        }
        float m0 = a0, m1 = a1;
#pragma unroll
        for (int off = 32; off; off >>= 1) {
            m0 = fmaxf(m0, __shfl_xor(m0, off, 64));
            m1 = fmaxf(m1, __shfl_xor(m1, off, 64));
        }
        float w0 = (lane < deg) ? __expf(a0 - m0) : 0.f;
        float w1 = (lane < deg) ? __expf(a1 - m1) : 0.f;
        float d0 = w0, d1 = w1;
#pragma unroll
        for (int off = 32; off; off >>= 1) {
            d0 += __shfl_xor(d0, off, 64);
            d1 += __shfl_xor(d1, off, 64);
        }
        if (lane < deg)
            ((float2*)wnorm)[e] = make_float2(w0 / (d0 + 1e-16f), w1 / (d1 + 1e-16f));
    } else {
        float m0 = -1e30f, m1 = -1e30f;
        for (int i = lane; i < deg; i += 64) {
            int s = csr[beg + i];
            float2 as = ((const float2*)a_src)[s];
            m0 = fmaxf(m0, lrelu(as.x + ad0));
            m1 = fmaxf(m1, lrelu(as.y + ad1));
        }
#pragma unroll
        for (int off = 32; off; off >>= 1) {
            m0 = fmaxf(m0, __shfl_xor(m0, off, 64));
            m1 = fmaxf(m1, __shfl_xor(m1, off, 64));
        }
        float d0 = 0.f, d1 = 0.f;
        for (int i = lane; i < deg; i += 64) {
            int s = csr[beg + i];
            float2 as = ((const float2*)a_src)[s];
            d0 += __expf(lrelu(as.x + ad0) - m0);
            d1 += __expf(lrelu(as.y + ad1) - m1);
        }
#pragma unroll
        for (int off = 32; off; off >>= 1) {
            d0 += __shfl_xor(d0, off, 64);
            d1 += __shfl_xor(d1, off, 64);
        }
        float inv0 = 1.f / (d0 + 1e-16f), inv1 = 1.f / (d1 + 1e-16f);
        for (int i = lane; i < deg; i += 64) {
            int s = csr[beg + i];
            float2 as = ((const float2*)a_src)[s];
            ((float2*)wnorm)[beg + i] =
                make_float2(__expf(lrelu(as.x + ad0) - m0) * inv0,
                            __expf(lrelu(as.y + ad1) - m1) * inv1);
        }
    }
}

// -------- aggregation, layer 1 (concat; fp16 row = 64 halves = 128B) --------

__global__ __launch_bounds__(256) void agg_concat_kernel(const __half* __restrict__ hg,
                                                         const float* __restrict__ wnorm,
                                                         const int* __restrict__ rowptr,
                                                         const int* __restrict__ csr,
                                                         const float* __restrict__ bias,
                                                         float* __restrict__ out, int N) {
    int node = blockIdx.x * 4 + (threadIdx.x >> 6);
    if (node >= N) return;
    int lane = threadIdx.x & 63;
    int g = lane >> 3, q = lane & 7;
    int beg = rowptr[node], end = rowptr[node + 1];
    float acc[8];
#pragma unroll
    for (int j = 0; j < 8; j++) acc[j] = 0.f;
    for (int e = beg + g; e < end; e += 8) {
        int s = csr[e];
        float2 wp = ((const float2*)wnorm)[e];
        float w = (q < 4) ? wp.x : wp.y;
        uint4 u = ((const uint4*)(hg + (size_t)s * 64))[q];
        float f[8];
        unpack8(u, f);
#pragma unroll
        for (int j = 0; j < 8; j++) acc[j] = fmaf(f[j], w, acc[j]);
    }
#pragma unroll
    for (int j = 0; j < 8; j++) {
        acc[j] += __shfl_xor(acc[j], 8, 64);
        acc[j] += __shfl_xor(acc[j], 16, 64);
        acc[j] += __shfl_xor(acc[j], 32, 64);
    }
    if (lane < 8) {
#pragma unroll
        for (int j4 = 0; j4 < 2; j4++) {
            float4 b = ((const float4*)bias)[2 * q + j4];
            float4 o;
            o.x = acc[4 * j4 + 0] + b.x;
            o.y = acc[4 * j4 + 1] + b.y;
            o.z = acc[4 * j4 + 2] + b.z;
            o.w = acc[4 * j4 + 3] + b.w;
            ((float4*)out)[(size_t)node * 16 + 2 * q + j4] = o;
        }
    }
}

// -------- aggregation, layer 2 (head-mean; fp16 row = 128 halves = 256B) --------

__global__ __launch_bounds__(256) void agg_mean_kernel(const __half* __restrict__ hg,
                                                       const float* __restrict__ wnorm,
                                                       const int* __restrict__ rowptr,
                                                       const int* __restrict__ csr,
                                                       const float* __restrict__ bias,
                                                       float* __restrict__ out, int N) {
    int node = blockIdx.x * 4 + (threadIdx.x >> 6);
    if (node >= N) return;
    int lane = threadIdx.x & 63;
    int g = lane >> 3, q = lane & 7;
    int beg = rowptr[node], end = rowptr[node + 1];
    float acc[16];
#pragma unroll
    for (int j = 0; j < 16; j++) acc[j] = 0.f;
    for (int e = beg + g; e < end; e += 8) {
        int s = csr[e];
        float2 wp = ((const float2*)wnorm)[e];
        float w = (q < 4) ? wp.x : wp.y;
        const uint4* row = (const uint4*)(hg + (size_t)s * 128);
        uint4 u0 = row[2 * q];
        uint4 u1 = row[2 * q + 1];
        float f[16];
        unpack8(u0, f);
        unpack8(u1, f + 8);
#pragma unroll
        for (int j = 0; j < 16; j++) acc[j] = fmaf(f[j], w, acc[j]);
    }
#pragma unroll
    for (int j = 0; j < 16; j++) {
        acc[j] += __shfl_xor(acc[j], 8, 64);
        acc[j] += __shfl_xor(acc[j], 16, 64);
        acc[j] += __shfl_xor(acc[j], 32, 64);
    }
    float part[16];
#pragma unroll
    for (int j = 0; j < 16; j++) part[j] = __shfl_xor(acc[j], 4, 64);
    if (lane < 4) {
#pragma unroll
        for (int j4 = 0; j4 < 4; j4++) {
            float4 b = ((const float4*)bias)[4 * q + j4];
            float4 o;
            o.x = 0.5f * (acc[4 * j4 + 0] + part[4 * j4 + 0]) + b.x;
            o.y = 0.5f * (acc[4 * j4 + 1] + part[4 * j4 + 1]) + b.y;
            o.z = 0.5f * (acc[4 * j4 + 2] + part[4 * j4 + 2]) + b.z;
            o.w = 0.5f * (acc[4 * j4 + 3] + part[4 * j4 + 3]) + b.w;
            ((float4*)out)[(size_t)node * 16 + 4 * q + j4] = o;
        }
    }
}

// ---------------- launch ----------------

extern "C" void kernel_launch(void* const* d_in, const int* in_sizes, int n_in,
                              void* d_out, int out_size, void* d_ws, size_t ws_size,
                              hipStream_t stream) {
    const float* x        = (const float*)d_in[0];
    const int*   ei       = (const int*)d_in[1];
    const float* W1       = (const float*)d_in[2];
    const float* att_src1 = (const float*)d_in[3];
    const float* att_dst1 = (const float*)d_in[4];
    const float* b1       = (const float*)d_in[5];
    const float* W2       = (const float*)d_in[6];
    const float* att_src2 = (const float*)d_in[7];
    const float* att_dst2 = (const float*)d_in[8];
    const float* b2       = (const float*)d_in[9];
    float* out = (float*)d_out;

    const int N = in_sizes[0] / 64;
    const int E = in_sizes[1] / 2;
    const int Etot = E + N;
    const int NBK = (N + 255) >> 8;
    const int NCH = (N + 511) >> 9;

    char* base = (char*)d_ws;
    size_t off = 0;
    auto alloc = [&](size_t bytes) -> char* {
        char* p = base + off;
        off = (off + bytes + 255) & ~(size_t)255;
        return p;
    };
    int*    deg    = (int*)alloc((size_t)N * 4);
    int*    rowptr = (int*)alloc((size_t)(N + 1) * 4);
    int*    csr    = (int*)alloc((size_t)Etot * 4);
    int*    bcur   = (int*)alloc((size_t)NBK * 4);
    int*    csum   = (int*)alloc((size_t)NCH * 4);
    uint2*  btmp   = (uint2*)alloc((size_t)Etot * 8);
    __half* h1g    = (__half*)alloc((size_t)N * 64 * 2);
    float*  asrc1  = (float*)alloc((size_t)N * 2 * 4);
    float*  adst1  = (float*)alloc((size_t)N * 2 * 4);
    float*  out1   = (float*)alloc((size_t)N * 64 * 4);
    __half* h2g    = (__half*)alloc((size_t)N * 128 * 2);
    float*  asrc2  = (float*)alloc((size_t)N * 2 * 4);
    float*  adst2  = (float*)alloc((size_t)N * 2 * 4);
    float*  wnorm  = (float*)alloc((size_t)Etot * 2 * 4);
    (void)ws_size; (void)n_in; (void)out_size;

    // CSR build (hierarchical scan + bucketed counting sort)
    hipMemsetAsync(deg, 0, (size_t)N * 4, stream);
    hist_kernel<<<(E + 255) / 256, 256, 0, stream>>>(ei + E, E, deg);
    scan_local_kernel<<<NCH, 256, 0, stream>>>(deg, rowptr, csum, N);
    scan_sums_kernel<<<1, 256, 0, stream>>>(csum, NCH);
    scan_add_kernel<<<NCH, 256, 0, stream>>>(csum, rowptr, N);
    initb_kernel<<<1, 256, 0, stream>>>(rowptr, bcur, NBK, N);
    bucketA_kernel<<<(Etot + 4095) / 4096, 256, 0, stream>>>(ei, E, Etot, bcur, btmp);
    bucketB_kernel<<<NBK, 256, 0, stream>>>(btmp, rowptr, N, csr);

    int nb4 = (N + 3) / 4;

    // layer 1 (att scores fused into GEMM epilogue)
    gemm64_kernel<64><<<(N + 31) / 32, 256, 0, stream>>>(x, W1, h1g, att_src1, att_dst1,
                                                         asrc1, adst1, N);
    edge_softmax_kernel<<<nb4, 256, 0, stream>>>(asrc1, adst1, rowptr, csr, wnorm, N);
    agg_concat_kernel<<<nb4, 256, 0, stream>>>(h1g, wnorm, rowptr, csr, b1, out1, N);

    // layer 2
    gemm64_kernel<128><<<(N + 15) / 16, 256, 0, stream>>>(out1, W2, h2g, att_src2, att_dst2,
                                                          asrc2, adst2, N);
    edge_softmax_kernel<<<nb4, 256, 0, stream>>>(asrc2, adst2, rowptr, csr, wnorm, N);
    agg_mean_kernel<<<nb4, 256, 0, stream>>>(h2g, wnorm, rowptr, csr, b2, out, N);
}

// Round 8
// 202.357 us; speedup vs baseline: 8.5438x; 1.0115x over previous
//
#include <hip/hip_runtime.h>
#include <hip/hip_fp16.h>

#define NEG_SLOPE 0.2f

__device__ __forceinline__ float lrelu(float a) { return a > 0.f ? a : NEG_SLOPE * a; }

struct half4 { __half2 a, b; };
__device__ __forceinline__ half4 pack_half4(float4 v) {
    half4 r; r.a = __floats2half2_rn(v.x, v.y); r.b = __floats2half2_rn(v.z, v.w); return r;
}
__device__ __forceinline__ void unpack8(uint4 u, float* f) {
    const __half2* hp = (const __half2*)&u;
#pragma unroll
    for (int i = 0; i < 4; i++) {
        float2 t = __half22float2(hp[i]);
        f[2 * i] = t.x; f[2 * i + 1] = t.y;
    }
}

// ---------------- CSR build ----------------

__global__ void zero_kernel(int4* __restrict__ p, int n4) {
    int i = blockIdx.x * blockDim.x + threadIdx.x;
    if (i < n4) p[i] = make_int4(0, 0, 0, 0);
}

__global__ void hist_kernel(const int* __restrict__ dst, int E, int* __restrict__ deg) {
    int i = blockIdx.x * blockDim.x + threadIdx.x;
    int stride = gridDim.x * blockDim.x;
    for (int e = i; e < E; e += stride) atomicAdd(&deg[dst[e]], 1);
}

// hierarchical exclusive scan of (deg[i]+1), chunk = 512 elements per 256-thread block
__global__ __launch_bounds__(256) void scan_local_kernel(const int* __restrict__ deg,
                                                         int* __restrict__ rowptr,
                                                         int* __restrict__ csum, int N) {
    __shared__ int wsum[4];
    int blk = blockIdx.x, t = threadIdx.x;
    int base = blk * 512;
    int i0 = base + 2 * t;
    int v0 = (i0 < N) ? deg[i0] + 1 : 0;
    int v1 = (i0 + 1 < N) ? deg[i0 + 1] + 1 : 0;
    int p = v0 + v1;
    int lane = t & 63, w = t >> 6;
    int s = p;
#pragma unroll
    for (int off = 1; off < 64; off <<= 1) {
        int x = __shfl_up(s, off, 64);
        if (lane >= off) s += x;
    }
    if (lane == 63) wsum[w] = s;
    __syncthreads();
    int woff = 0;
    if (w > 0) woff += wsum[0];
    if (w > 1) woff += wsum[1];
    if (w > 2) woff += wsum[2];
    int epre = woff + s - p;  // exclusive prefix for this pair
    if (i0 < N)     rowptr[i0 + 1] = epre + v0;
    if (i0 + 1 < N) rowptr[i0 + 2] = epre + v0 + v1;
    if (t == 255) csum[blk] = woff + s;
}

__global__ __launch_bounds__(256) void scan_sums_kernel(int* __restrict__ csum, int NCH) {
    __shared__ int wsum[4];
    int t = threadIdx.x, lane = t & 63, w = t >> 6;
    int v = (t < NCH) ? csum[t] : 0;
    int s = v;
#pragma unroll
    for (int off = 1; off < 64; off <<= 1) {
        int x = __shfl_up(s, off, 64);
        if (lane >= off) s += x;
    }
    if (lane == 63) wsum[w] = s;
    __syncthreads();
    int woff = 0;
    if (w > 0) woff += wsum[0];
    if (w > 1) woff += wsum[1];
    if (w > 2) woff += wsum[2];
    if (t < NCH) csum[t] = woff + s - v;  // exclusive
}

// adds chunk offsets; also emits bcur[bk] = rowptr[bk*256] (bucket cursor init)
__global__ __launch_bounds__(256) void scan_add_kernel(const int* __restrict__ csum,
                                                       int* __restrict__ rowptr,
                                                       int* __restrict__ bcur, int N) {
    int blk = blockIdx.x, t = threadIdx.x;
    int off = csum[blk];
    int i0 = blk * 512 + 2 * t;
    if (blk == 0 && t == 0) { rowptr[0] = 0; bcur[0] = 0; }
    if (i0 < N) {
        int v = rowptr[i0 + 1] + off;
        rowptr[i0 + 1] = v;
        if (((i0 + 1) & 255) == 0) bcur[(i0 + 1) >> 8] = v;
    }
    if (i0 + 1 < N) {
        int v = rowptr[i0 + 2] + off;
        rowptr[i0 + 2] = v;
        if (((i0 + 2) & 255) == 0) bcur[(i0 + 2) >> 8] = v;
    }
}

// Pass A: tile 4096 edges/block; LDS histogram over buckets; reserve dense per-
// (block,bucket) ranges via one global atomic each; write (src,dst) runs.
__global__ __launch_bounds__(256) void bucketA_kernel(const int* __restrict__ ei, int E,
                                                      int Etot, int* __restrict__ bcur,
                                                      uint2* __restrict__ btmp) {
    __shared__ int lh[256];
    __shared__ int lbase[256];
    int t = threadIdx.x;
    int b0 = blockIdx.x * 4096;
    lh[t] = 0;
    __syncthreads();
    int s[16], d[16], bk[16];
#pragma unroll
    for (int i = 0; i < 16; i++) {
        int e = b0 + i * 256 + t;
        if (e < Etot) {
            int ss, dd;
            if (e < E) { ss = ei[e]; dd = ei[E + e]; }
            else       { ss = e - E; dd = ss; }
            s[i] = ss; d[i] = dd; bk[i] = dd >> 8;
            atomicAdd(&lh[bk[i]], 1);
        } else bk[i] = -1;
    }
    __syncthreads();
    if (lh[t] > 0) lbase[t] = atomicAdd(&bcur[t], lh[t]);
    __syncthreads();
    lh[t] = 0;
    __syncthreads();
#pragma unroll
    for (int i = 0; i < 16; i++) {
        if (bk[i] >= 0) {
            int pos = lbase[bk[i]] + atomicAdd(&lh[bk[i]], 1);
            btmp[pos] = make_uint2((unsigned)s[i], (unsigned)d[i]);
        }
    }
}

// Pass B: one block per bucket; per-node cursors + rowptr slice in LDS.
__global__ __launch_bounds__(256) void bucketB_kernel(const uint2* __restrict__ btmp,
                                                      const int* __restrict__ rowptr,
                                                      int N, int* __restrict__ csr) {
    __shared__ int lcur[256];
    __shared__ int lrow[257];
    int bkt = blockIdx.x;
    int n0 = bkt << 8;
    int n1 = n0 + 256; if (n1 > N) n1 = N;
    int nn = n1 - n0;
    int t = threadIdx.x;
    lcur[t] = 0;
    if (t < nn) lrow[t] = rowptr[n0 + t];
    if (t == 0) lrow[nn] = rowptr[n1];
    __syncthreads();
    int ebeg = lrow[0], eend = lrow[nn];
    for (int e = ebeg + t; e < eend; e += 256) {
        uint2 sd = btmp[e];
        int dl = (int)sd.y - n0;
        int slot = atomicAdd(&lcur[dl], 1);
        csr[lrow[dl] + slot] = (int)sd.x;
    }
}

// ------- GEMM + fused att scores: Yh = fp16(X @ W), a_src/a_dst [N,2] -------

template <int M>
__global__ __launch_bounds__(256) void gemm64_kernel(const float* __restrict__ X,
                                                     const float* __restrict__ W,
                                                     __half* __restrict__ Yh,
                                                     const float* __restrict__ att_s,
                                                     const float* __restrict__ att_d,
                                                     float* __restrict__ a_src,
                                                     float* __restrict__ a_dst, int N) {
    constexpr int CG = M / 4;
    constexpr int RB = (256 / CG) * 2;
    constexpr int HL = CG / 2;  // lanes per head group: 8 (M=64) or 16 (M=128)
    __shared__ float4 ws[64 * CG];
    __shared__ float  xs[RB][68];
    int t = threadIdx.x;
    for (int i = t; i < 64 * CG; i += 256) ws[i] = ((const float4*)W)[i];
    int r0 = blockIdx.x * RB;
    for (int i = t; i < RB * 16; i += 256) {
        int r = i >> 4, k4 = i & 15;
        int row = r0 + r;
        float4 v = (row < N) ? ((const float4*)X)[(size_t)row * 16 + k4]
                             : make_float4(0.f, 0.f, 0.f, 0.f);
        ((float4*)&xs[r][0])[k4] = v;
    }
    __syncthreads();
    int c = t % CG;
    int rl = (t / CG) * 2;
    float4 a0 = make_float4(0.f, 0.f, 0.f, 0.f);
    float4 a1 = make_float4(0.f, 0.f, 0.f, 0.f);
#pragma unroll 8
    for (int k = 0; k < 64; k++) {
        float4 w = ws[k * CG + c];
        float x0 = xs[rl][k];
        float x1 = xs[rl + 1][k];
        a0.x = fmaf(x0, w.x, a0.x); a0.y = fmaf(x0, w.y, a0.y);
        a0.z = fmaf(x0, w.z, a0.z); a0.w = fmaf(x0, w.w, a0.w);
        a1.x = fmaf(x1, w.x, a1.x); a1.y = fmaf(x1, w.y, a1.y);
        a1.z = fmaf(x1, w.z, a1.z); a1.w = fmaf(x1, w.w, a1.w);
    }
    int row0 = r0 + rl;
    if (row0 < N)     ((half4*)Yh)[(size_t)row0 * CG + c] = pack_half4(a0);
    if (row0 + 1 < N) ((half4*)Yh)[(size_t)(row0 + 1) * CG + c] = pack_half4(a1);

    // fused attention scores (per-head dot + 8/16-lane reduce)
    float4 s4 = ((const float4*)att_s)[c];
    float4 d4 = ((const float4*)att_d)[c];
    float vs0 = a0.x * s4.x + a0.y * s4.y + a0.z * s4.z + a0.w * s4.w;
    float vd0 = a0.x * d4.x + a0.y * d4.y + a0.z * d4.z + a0.w * d4.w;
    float vs1 = a1.x * s4.x + a1.y * s4.y + a1.z * s4.z + a1.w * s4.w;
    float vd1 = a1.x * d4.x + a1.y * d4.y + a1.z * d4.z + a1.w * d4.w;
#pragma unroll
    for (int off = 1; off < HL; off <<= 1) {
        vs0 += __shfl_xor(vs0, off, 64);
        vd0 += __shfl_xor(vd0, off, 64);
        vs1 += __shfl_xor(vs1, off, 64);
        vd1 += __shfl_xor(vd1, off, 64);
    }
    if ((c & (HL - 1)) == 0) {
        int hh = c / HL;
        if (row0 < N)     { a_src[row0 * 2 + hh] = vs0; a_dst[row0 * 2 + hh] = vd0; }
        if (row0 + 1 < N) { a_src[(row0 + 1) * 2 + hh] = vs1; a_dst[(row0 + 1) * 2 + hh] = vd1; }
    }
}

// ---------------- edge softmax: normalized weights in CSR order ----------------

__global__ __launch_bounds__(256) void edge_softmax_kernel(const float* __restrict__ a_src,
                                                           const float* __restrict__ a_dst,
                                                           const int* __restrict__ rowptr,
                                                           const int* __restrict__ csr,
                                                           float* __restrict__ wnorm,
                                                           int N) {
    int node = blockIdx.x * 4 + (threadIdx.x >> 6);
    int lane = threadIdx.x & 63;
    if (node >= N) return;
    int beg = rowptr[node], end = rowptr[node + 1];
    int deg = end - beg;
    float ad0 = a_dst[node * 2 + 0];
    float ad1 = a_dst[node * 2 + 1];
    if (deg <= 64) {
        float a0 = -1e30f, a1 = -1e30f;
        int e = beg + lane;
        if (lane < deg) {
            int s = csr[e];
            float2 as = ((const float2*)a_src)[s];
            a0 = lrelu(as.x + ad0);
            a1 = lrelu(as.y + ad1);
        }
        float m0 = a0, m1 = a1;
#pragma unroll
        for (int off = 32; off; off >>= 1) {
            m0 = fmaxf(m0, __shfl_xor(m0, off, 64));
            m1 = fmaxf(m1, __shfl_xor(m1, off, 64));
        }
        float w0 = (lane < deg) ? __expf(a0 - m0) : 0.f;
        float w1 = (lane < deg) ? __expf(a1 - m1) : 0.f;
        float d0 = w0, d1 = w1;
#pragma unroll
        for (int off = 32; off; off >>= 1) {
            d0 += __shfl_xor(d0, off, 64);
            d1 += __shfl_xor(d1, off, 64);
        }
        if (lane < deg)
            ((float2*)wnorm)[e] = make_float2(w0 / (d0 + 1e-16f), w1 / (d1 + 1e-16f));
    } else {
        float m0 = -1e30f, m1 = -1e30f;
        for (int i = lane; i < deg; i += 64) {
            int s = csr[beg + i];
            float2 as = ((const float2*)a_src)[s];
            m0 = fmaxf(m0, lrelu(as.x + ad0));
            m1 = fmaxf(m1, lrelu(as.y + ad1));
        }
#pragma unroll
        for (int off = 32; off; off >>= 1) {
            m0 = fmaxf(m0, __shfl_xor(m0, off, 64));
            m1 = fmaxf(m1, __shfl_xor(m1, off, 64));
        }
        float d0 = 0.f, d1 = 0.f;
        for (int i = lane; i < deg; i += 64) {
            int s = csr[beg + i];
            float2 as = ((const float2*)a_src)[s];
            d0 += __expf(lrelu(as.x + ad0) - m0);
            d1 += __expf(lrelu(as.y + ad1) - m1);
        }
#pragma unroll
        for (int off = 32; off; off >>= 1) {
            d0 += __shfl_xor(d0, off, 64);
            d1 += __shfl_xor(d1, off, 64);
        }
        float inv0 = 1.f / (d0 + 1e-16f), inv1 = 1.f / (d1 + 1e-16f);
        for (int i = lane; i < deg; i += 64) {
            int s = csr[beg + i];
            float2 as = ((const float2*)a_src)[s];
            ((float2*)wnorm)[beg + i] =
                make_float2(__expf(lrelu(as.x + ad0) - m0) * inv0,
                            __expf(lrelu(as.y + ad1) - m1) * inv1);
        }
    }
}

// -------- aggregation, layer 1 (concat; fp16 row = 64 halves = 128B) --------

__global__ __launch_bounds__(256) void agg_concat_kernel(const __half* __restrict__ hg,
                                                         const float* __restrict__ wnorm,
                                                         const int* __restrict__ rowptr,
                                                         const int* __restrict__ csr,
                                                         const float* __restrict__ bias,
                                                         float* __restrict__ out, int N) {
    int node = blockIdx.x * 4 + (threadIdx.x >> 6);
    if (node >= N) return;
    int lane = threadIdx.x & 63;
    int g = lane >> 3, q = lane & 7;
    int beg = rowptr[node], end = rowptr[node + 1];
    float acc[8];
#pragma unroll
    for (int j = 0; j < 8; j++) acc[j] = 0.f;
    for (int e = beg + g; e < end; e += 8) {
        int s = csr[e];
        float2 wp = ((const float2*)wnorm)[e];
        float w = (q < 4) ? wp.x : wp.y;
        uint4 u = ((const uint4*)(hg + (size_t)s * 64))[q];
        float f[8];
        unpack8(u, f);
#pragma unroll
        for (int j = 0; j < 8; j++) acc[j] = fmaf(f[j], w, acc[j]);
    }
#pragma unroll
    for (int j = 0; j < 8; j++) {
        acc[j] += __shfl_xor(acc[j], 8, 64);
        acc[j] += __shfl_xor(acc[j], 16, 64);
        acc[j] += __shfl_xor(acc[j], 32, 64);
    }
    if (lane < 8) {
#pragma unroll
        for (int j4 = 0; j4 < 2; j4++) {
            float4 b = ((const float4*)bias)[2 * q + j4];
            float4 o;
            o.x = acc[4 * j4 + 0] + b.x;
            o.y = acc[4 * j4 + 1] + b.y;
            o.z = acc[4 * j4 + 2] + b.z;
            o.w = acc[4 * j4 + 3] + b.w;
            ((float4*)out)[(size_t)node * 16 + 2 * q + j4] = o;
        }
    }
}

// -------- aggregation, layer 2 (head-mean; fp16 row = 128 halves = 256B) --------

__global__ __launch_bounds__(256) void agg_mean_kernel(const __half* __restrict__ hg,
                                                       const float* __restrict__ wnorm,
                                                       const int* __restrict__ rowptr,
                                                       const int* __restrict__ csr,
                                                       const float* __restrict__ bias,
                                                       float* __restrict__ out, int N) {
    int node = blockIdx.x * 4 + (threadIdx.x >> 6);
    if (node >= N) return;
    int lane = threadIdx.x & 63;
    int g = lane >> 3, q = lane & 7;
    int beg = rowptr[node], end = rowptr[node + 1];
    float acc[16];
#pragma unroll
    for (int j = 0; j < 16; j++) acc[j] = 0.f;
    for (int e = beg + g; e < end; e += 8) {
        int s = csr[e];
        float2 wp = ((const float2*)wnorm)[e];
        float w = (q < 4) ? wp.x : wp.y;
        const uint4* row = (const uint4*)(hg + (size_t)s * 128);
        uint4 u0 = row[2 * q];
        uint4 u1 = row[2 * q + 1];
        float f[16];
        unpack8(u0, f);
        unpack8(u1, f + 8);
#pragma unroll
        for (int j = 0; j < 16; j++) acc[j] = fmaf(f[j], w, acc[j]);
    }
#pragma unroll
    for (int j = 0; j < 16; j++) {
        acc[j] += __shfl_xor(acc[j], 8, 64);
        acc[j] += __shfl_xor(acc[j], 16, 64);
        acc[j] += __shfl_xor(acc[j], 32, 64);
    }
    float part[16];
#pragma unroll
    for (int j = 0; j < 16; j++) part[j] = __shfl_xor(acc[j], 4, 64);
    if (lane < 4) {
#pragma unroll
        for (int j4 = 0; j4 < 4; j4++) {
            float4 b = ((const float4*)bias)[4 * q + j4];
            float4 o;
            o.x = 0.5f * (acc[4 * j4 + 0] + part[4 * j4 + 0]) + b.x;
            o.y = 0.5f * (acc[4 * j4 + 1] + part[4 * j4 + 1]) + b.y;
            o.z = 0.5f * (acc[4 * j4 + 2] + part[4 * j4 + 2]) + b.z;
            o.w = 0.5f * (acc[4 * j4 + 3] + part[4 * j4 + 3]) + b.w;
            ((float4*)out)[(size_t)node * 16 + 4 * q + j4] = o;
        }
    }
}

// ---------------- launch ----------------

extern "C" void kernel_launch(void* const* d_in, const int* in_sizes, int n_in,
                              void* d_out, int out_size, void* d_ws, size_t ws_size,
                              hipStream_t stream) {
    const float* x        = (const float*)d_in[0];
    const int*   ei       = (const int*)d_in[1];
    const float* W1       = (const float*)d_in[2];
    const float* att_src1 = (const float*)d_in[3];
    const float* att_dst1 = (const float*)d_in[4];
    const float* b1       = (const float*)d_in[5];
    const float* W2       = (const float*)d_in[6];
    const float* att_src2 = (const float*)d_in[7];
    const float* att_dst2 = (const float*)d_in[8];
    const float* b2       = (const float*)d_in[9];
    float* out = (float*)d_out;

    const int N = in_sizes[0] / 64;
    const int E = in_sizes[1] / 2;
    const int Etot = E + N;
    const int NBK = (N + 255) >> 8;
    const int NCH = (N + 511) >> 9;

    char* base = (char*)d_ws;
    size_t off = 0;
    auto alloc = [&](size_t bytes) -> char* {
        char* p = base + off;
        off = (off + bytes + 255) & ~(size_t)255;
        return p;
    };
    int*    deg    = (int*)alloc((size_t)N * 4);
    int*    rowptr = (int*)alloc((size_t)(N + 1) * 4);
    int*    csr    = (int*)alloc((size_t)Etot * 4);
    int*    bcur   = (int*)alloc((size_t)NBK * 4);
    int*    csum   = (int*)alloc((size_t)NCH * 4);
    uint2*  btmp   = (uint2*)alloc((size_t)Etot * 8);
    __half* h1g    = (__half*)alloc((size_t)N * 64 * 2);
    float*  asrc1  = (float*)alloc((size_t)N * 2 * 4);
    float*  adst1  = (float*)alloc((size_t)N * 2 * 4);
    float*  out1   = (float*)alloc((size_t)N * 64 * 4);
    __half* h2g    = (__half*)alloc((size_t)N * 128 * 2);
    float*  asrc2  = (float*)alloc((size_t)N * 2 * 4);
    float*  adst2  = (float*)alloc((size_t)N * 2 * 4);
    float*  wnorm  = (float*)alloc((size_t)Etot * 2 * 4);
    (void)ws_size; (void)n_in; (void)out_size;

    // CSR build (hierarchical scan + bucketed counting sort)
    int n4 = (N + 3) / 4;
    zero_kernel<<<(n4 + 255) / 256, 256, 0, stream>>>((int4*)deg, n4);
    hist_kernel<<<(E + 255) / 256, 256, 0, stream>>>(ei + E, E, deg);
    scan_local_kernel<<<NCH, 256, 0, stream>>>(deg, rowptr, csum, N);
    scan_sums_kernel<<<1, 256, 0, stream>>>(csum, NCH);
    scan_add_kernel<<<NCH, 256, 0, stream>>>(csum, rowptr, bcur, N);
    bucketA_kernel<<<(Etot + 4095) / 4096, 256, 0, stream>>>(ei, E, Etot, bcur, btmp);
    bucketB_kernel<<<NBK, 256, 0, stream>>>(btmp, rowptr, N, csr);

    int nb4 = (N + 3) / 4;

    // layer 1 (att scores fused into GEMM epilogue)
    gemm64_kernel<64><<<(N + 31) / 32, 256, 0, stream>>>(x, W1, h1g, att_src1, att_dst1,
                                                         asrc1, adst1, N);
    edge_softmax_kernel<<<nb4, 256, 0, stream>>>(asrc1, adst1, rowptr, csr, wnorm, N);
    agg_concat_kernel<<<nb4, 256, 0, stream>>>(h1g, wnorm, rowptr, csr, b1, out1, N);

    // layer 2
    gemm64_kernel<128><<<(N + 15) / 16, 256, 0, stream>>>(out1, W2, h2g, att_src2, att_dst2,
                                                          asrc2, adst2, N);
    edge_softmax_kernel<<<nb4, 256, 0, stream>>>(asrc2, adst2, rowptr, csr, wnorm, N);
    agg_mean_kernel<<<nb4, 256, 0, stream>>>(h2g, wnorm, rowptr, csr, b2, out, N);
}